// Round 1
// baseline (999.471 us; speedup 1.0000x reference)
//
#include <hip/hip_runtime.h>
#include <cstddef>

// Problem constants
// B=8, DIM=256, NH=8, H=W=56, G=4, CG=64, GH=2, HC=32, Hk=Wk=8, ns=64

// ws float offsets
#define OFF_FEAT 0u            // 6422528 floats (reused as attention-out after sampling)
#define OFF_Q    6422528u      // 6422528
#define OFF_POS  12845056u     // 4096
#define OFF_XS   12849152u     // 131072
#define OFF_K    12980224u     // 131072
#define OFF_V    13111296u     // 131072

// ---------------------------------------------------------------------------
// Kernel A: patch embedding conv (3->256, 8x8, stride 8) + bias + LayerNorm over channels
// block = 256 threads (one per out channel), 8 spatial positions per block
__global__ __launch_bounds__(256) void k_patch_ln(
    const float* __restrict__ x, const float* __restrict__ pw,
    const float* __restrict__ pb, const float* __restrict__ g1,
    const float* __restrict__ b1, float* __restrict__ feat) {
  const int t = threadIdx.x;
  const int P0 = blockIdx.x * 8;           // flat position, 25088 total
  const int b = P0 / 3136;
  const int rem = P0 % 3136;
  const int oh = rem / 56;
  const int ow0 = rem % 56;                // multiple of 8

  __shared__ float sx[24 * 64];            // [ci*8+i][64 cols]
  for (int idx = t; idx < 24 * 64; idx += 256) {
    int rr = idx >> 6, cc = idx & 63;
    int ci = rr >> 3, i = rr & 7;
    sx[idx] = x[(((size_t)b * 3 + ci) * 448 + (oh * 8 + i)) * 448 + ow0 * 8 + cc];
  }
  __syncthreads();

  float acc[8];
#pragma unroll
  for (int p = 0; p < 8; p++) acc[p] = 0.f;
  const float* wrow = pw + t * 192;
  for (int r = 0; r < 192; r++) {
    float w = wrow[r];
    const float* s = &sx[(r >> 3) * 64 + (r & 7)];
#pragma unroll
    for (int p = 0; p < 8; p++) acc[p] = fmaf(w, s[p * 8], acc[p]);
  }
  float bias = pb[t];

  __shared__ float cv[8][257];
#pragma unroll
  for (int p = 0; p < 8; p++) cv[p][t] = acc[p] + bias;
  __syncthreads();

  // LN reduce: 32 threads per position
  int p = t >> 5, lane = t & 31;
  float s1 = 0.f, s2 = 0.f;
#pragma unroll
  for (int k = 0; k < 8; k++) {
    float v = cv[p][lane + k * 32];
    s1 += v; s2 += v * v;
  }
#pragma unroll
  for (int off = 16; off >= 1; off >>= 1) {
    s1 += __shfl_xor(s1, off);
    s2 += __shfl_xor(s2, off);
  }
  __shared__ float mean_s[8], rstd_s[8];
  if (lane == 0) {
    float m = s1 * (1.f / 256.f);
    float var = s2 * (1.f / 256.f) - m * m;
    mean_s[p] = m;
    rstd_s[p] = rsqrtf(var + 1e-5f);
  }
  __syncthreads();
  float gg = g1[t], bb = b1[t];
  size_t base = ((size_t)b * 256 + t) * 3136 + oh * 56 + ow0;
#pragma unroll
  for (int q = 0; q < 8; q++)
    feat[base + q] = (cv[q][t] - mean_s[q]) * rstd_s[q] * gg + bb;
}

// ---------------------------------------------------------------------------
// Kernel B: out[b,o,m] = sum_c w[o,c]*in[b,c,m] + bias[o]  (256x256, 25088 positions)
// block = 256 threads (one per out channel), 16 positions per block
__global__ __launch_bounds__(256) void k_gemm256(
    const float* __restrict__ in, const float* __restrict__ w,
    const float* __restrict__ bias, float* __restrict__ out) {
  const int t = threadIdx.x;
  const int P0 = blockIdx.x * 16;
  const int b = P0 / 3136;
  const int m0 = P0 % 3136;

  __shared__ float si[256][16];
  {
    const float4* src = (const float4*)(in + ((size_t)b * 256 + t) * 3136 + m0);
    float4 a0 = src[0], a1 = src[1], a2 = src[2], a3 = src[3];
    float* d = si[t];
    *(float4*)(d + 0) = a0; *(float4*)(d + 4) = a1;
    *(float4*)(d + 8) = a2; *(float4*)(d + 12) = a3;
  }
  __syncthreads();

  float acc[16];
  float bv = bias[t];
#pragma unroll
  for (int j = 0; j < 16; j++) acc[j] = bv;
  const float* wr = w + t * 256;
  for (int c = 0; c < 256; c++) {
    float wv = wr[c];
    const float* s = si[c];
#pragma unroll
    for (int j = 0; j < 16; j++) acc[j] = fmaf(wv, s[j], acc[j]);
  }
  float* op = out + ((size_t)b * 256 + t) * 3136 + m0;
#pragma unroll
  for (int j = 0; j < 16; j++) op[j] = acc[j];
}

// ---------------------------------------------------------------------------
// Kernel C: offset network. One wave (64 lanes = 64 group-channels) per output
// position. Depthwise 28x28/s8/p14 conv + LN(64) + GELU + pointwise(2x64) +
// tanh scaling + reference points. Writes pos to ws and pos/ref to d_out.
__global__ __launch_bounds__(256) void k_offset(
    const float* __restrict__ q, const float* __restrict__ dww,
    const float* __restrict__ dwb, const float* __restrict__ lng,
    const float* __restrict__ lnb, const float* __restrict__ pww,
    float* __restrict__ pos_ws, float* __restrict__ out_pos,
    float* __restrict__ out_ref) {
  const int bg = blockIdx.y;               // 0..31
  const int wv = threadIdx.x >> 6;         // 0..3
  const int lane = threadIdx.x & 63;       // cg
  const int idx = blockIdx.x * 4 + wv;     // 0..63
  const int oh = idx >> 3, ow = idx & 7;
  const int b = bg >> 2, g = bg & 3;

  const float* qb = q + ((size_t)b * 256 + g * 64 + lane) * 3136;
  const float* wr = dww + lane * 784;
  float acc = dwb[lane];
  const int ybase = oh * 8 - 14, xbase = ow * 8 - 14;
  const int ilo = max(0, -ybase), ihi = min(28, 56 - ybase);
  const int jlo = max(0, -xbase), jhi = min(28, 56 - xbase);
  for (int i = ilo; i < ihi; i++) {
    const float* qrow = qb + (ybase + i) * 56;
    const float* wrr = wr + i * 28;
    for (int j = jlo; j < jhi; j++)
      acc = fmaf(qrow[xbase + j], wrr[j], acc);
  }

  // LN over 64 lanes
  float s1 = acc, s2 = acc * acc;
#pragma unroll
  for (int off = 32; off >= 1; off >>= 1) {
    s1 += __shfl_xor(s1, off);
    s2 += __shfl_xor(s2, off);
  }
  float m = s1 * (1.f / 64.f);
  float var = s2 * (1.f / 64.f) - m * m;
  float val = (acc - m) * rsqrtf(var + 1e-5f) * lng[lane] + lnb[lane];
  // exact gelu
  val = 0.5f * val * (1.f + erff(val * 0.70710678118654752f));
  // pointwise 2x64
  float p0 = pww[lane] * val, p1 = pww[64 + lane] * val;
#pragma unroll
  for (int off = 32; off >= 1; off >>= 1) {
    p0 += __shfl_xor(p0, off);
    p1 += __shfl_xor(p1, off);
  }
  if (lane == 0) {
    float offy = tanhf(p0) * (2.0f / 7.0f);   // rng * ORF = (1/7)*2
    float offx = tanhf(p1) * (2.0f / 7.0f);
    float ry = (0.5f + oh) * (2.0f / 7.0f) - 1.0f;
    float rx = (0.5f + ow) * (2.0f / 7.0f) - 1.0f;
    float py = offy + ry, px = offx + rx;
    int o = bg * 128 + idx * 2;
    pos_ws[o] = py;  pos_ws[o + 1] = px;
    out_pos[o] = py; out_pos[o + 1] = px;
    out_ref[o] = ry; out_ref[o + 1] = rx;
  }
}

// ---------------------------------------------------------------------------
// Kernel D: bilinear sampling. One wave (64 group-channels) per sample point.
__global__ __launch_bounds__(256) void k_sample(
    const float* __restrict__ feat, const float* __restrict__ pos_ws,
    float* __restrict__ xs) {
  const int bg = blockIdx.y;
  const int wv = threadIdx.x >> 6, lane = threadIdx.x & 63;
  const int n = blockIdx.x * 4 + wv;
  const int b = bg >> 2, g = bg & 3;

  float py = pos_ws[bg * 128 + n * 2];
  float px = pos_ws[bg * 128 + n * 2 + 1];
  float gx = (px + 1.f) * 0.5f * 55.f;
  float gy = (py + 1.f) * 0.5f * 55.f;
  float x0f = floorf(gx), y0f = floorf(gy);
  int x0 = (int)x0f, y0 = (int)y0f;
  float wx1 = gx - x0f, wx0 = 1.f - wx1;
  float wy1 = gy - y0f, wy0 = 1.f - wy1;

  const float* fb = feat + ((size_t)b * 256 + g * 64 + lane) * 3136;
  float acc = 0.f;
  if (x0 >= 0 && x0 <= 55 && y0 >= 0 && y0 <= 55)       acc = fmaf(fb[y0 * 56 + x0],           wx0 * wy0, acc);
  if (x0 + 1 >= 0 && x0 + 1 <= 55 && y0 >= 0 && y0 <= 55)   acc = fmaf(fb[y0 * 56 + x0 + 1],       wx1 * wy0, acc);
  if (x0 >= 0 && x0 <= 55 && y0 + 1 >= 0 && y0 + 1 <= 55)   acc = fmaf(fb[(y0 + 1) * 56 + x0],     wx0 * wy1, acc);
  if (x0 + 1 >= 0 && x0 + 1 <= 55 && y0 + 1 >= 0 && y0 + 1 <= 55) acc = fmaf(fb[(y0 + 1) * 56 + x0 + 1], wx1 * wy1, acc);

  xs[((size_t)bg * 64 + lane) * 64 + n] = acc;
}

// ---------------------------------------------------------------------------
// Kernel E: k,v projections on sampled features. One block per (b, n).
__global__ __launch_bounds__(256) void k_kv(
    const float* __restrict__ xs, const float* __restrict__ wk,
    const float* __restrict__ bk, const float* __restrict__ wv_,
    const float* __restrict__ bv, float* __restrict__ ko,
    float* __restrict__ vo) {
  const int b = blockIdx.y;   // 0..7
  const int n = blockIdx.x;   // 0..63
  const int t = threadIdx.x;
  __shared__ float sxs[256];
  sxs[t] = xs[((size_t)b * 256 + t) * 64 + n];
  __syncthreads();
  float ak = bk[t], av = bv[t];
  const float* wkr = wk + t * 256;
  const float* wvr = wv_ + t * 256;
  for (int c = 0; c < 256; c++) {
    float xv = sxs[c];
    ak = fmaf(wkr[c], xv, ak);
    av = fmaf(wvr[c], xv, av);
  }
  ko[((size_t)b * 256 + t) * 64 + n] = ak;
  vo[((size_t)b * 256 + t) * 64 + n] = av;
}

// ---------------------------------------------------------------------------
// Kernel F: attention. One thread per query; K/V/pos/rpe staged in LDS.
__global__ __launch_bounds__(256) void k_attn(
    const float* __restrict__ qws, const float* __restrict__ kws,
    const float* __restrict__ vws, const float* __restrict__ pos_ws,
    const float* __restrict__ w1, const float* __restrict__ b1,
    const float* __restrict__ w2, float* __restrict__ ows) {
  const int bh = blockIdx.y;          // 0..63
  const int b = bh >> 3, h = bh & 7;
  const int g = h >> 1, gh = h & 1;
  const int bg = b * 4 + g;
  const int t = threadIdx.x;

  __shared__ float Kt[64][36];        // [n][cc], padded for alignment/banks
  __shared__ float Vt[64][36];
  __shared__ float posl[128];
  __shared__ float rpe4[32][4];       // {w1y, w1x, b1, w2[gh]}

  const float* kp = kws + ((size_t)b * 256 + h * 32) * 64;
  const float* vp = vws + ((size_t)b * 256 + h * 32) * 64;
  for (int i = t; i < 2048; i += 256) {
    int cc = i >> 6, n = i & 63;
    Kt[n][cc] = kp[i];
    Vt[n][cc] = vp[i];
  }
  if (t < 128) posl[t] = pos_ws[bg * 128 + t];
  if (t < 32) {
    rpe4[t][0] = w1[t * 2];
    rpe4[t][1] = w1[t * 2 + 1];
    rpe4[t][2] = b1[t];
    rpe4[t][3] = w2[gh * 32 + t];
  }
  __syncthreads();

  const int m = blockIdx.x * 256 + t;
  if (m >= 3136) return;
  const int my = m / 56, mx = m % 56;
  const float qgy = ((float)my * (56.0f / 55.0f)) * (2.0f / 55.0f) - 1.0f;
  const float qgx = ((float)mx * (56.0f / 55.0f)) * (2.0f / 55.0f) - 1.0f;

  float qv[32];
  const float* qp = qws + ((size_t)b * 256 + h * 32) * 3136 + m;
#pragma unroll
  for (int cc = 0; cc < 32; cc++) qv[cc] = qp[cc * 3136];

  const float scale = 0.17677669529663687f;  // 1/sqrt(32)
  float p[64];
  float mmax = -1e30f;
#pragma unroll
  for (int n = 0; n < 64; n++) {
    float s = 0.f;
    const float4* kk = (const float4*)Kt[n];
#pragma unroll
    for (int c4 = 0; c4 < 8; c4++) {
      float4 kv = kk[c4];
      s = fmaf(qv[c4 * 4 + 0], kv.x, s);
      s = fmaf(qv[c4 * 4 + 1], kv.y, s);
      s = fmaf(qv[c4 * 4 + 2], kv.z, s);
      s = fmaf(qv[c4 * 4 + 3], kv.w, s);
    }
    s *= scale;
    float dy = (qgy - posl[n * 2]) * 4.f;
    float dx = (qgx - posl[n * 2 + 1]) * 4.f;
    float ty = copysignf(log2f(fabsf(dy) + 1.f) * (1.f / 3.f), dy);
    float tx = copysignf(log2f(fabsf(dx) + 1.f) * (1.f / 3.f), dx);
    float biasv = 0.f;
#pragma unroll
    for (int j = 0; j < 32; j++) {
      float4 r = *(const float4*)rpe4[j];
      float hv = fmaf(r.x, ty, fmaf(r.y, tx, r.z));
      hv = fmaxf(hv, 0.f);
      biasv = fmaf(r.w, hv, biasv);
    }
    s += biasv;
    p[n] = s;
    mmax = fmaxf(mmax, s);
  }
  float sum = 0.f;
#pragma unroll
  for (int n = 0; n < 64; n++) {
    float e = __expf(p[n] - mmax);
    p[n] = e;
    sum += e;
  }
  float inv = 1.f / sum;

  float acc[32];
#pragma unroll
  for (int cc = 0; cc < 32; cc++) acc[cc] = 0.f;
#pragma unroll
  for (int n = 0; n < 64; n++) {
    float pw_ = p[n];
    const float4* vv = (const float4*)Vt[n];
#pragma unroll
    for (int c4 = 0; c4 < 8; c4++) {
      float4 v4 = vv[c4];
      acc[c4 * 4 + 0] = fmaf(pw_, v4.x, acc[c4 * 4 + 0]);
      acc[c4 * 4 + 1] = fmaf(pw_, v4.y, acc[c4 * 4 + 1]);
      acc[c4 * 4 + 2] = fmaf(pw_, v4.z, acc[c4 * 4 + 2]);
      acc[c4 * 4 + 3] = fmaf(pw_, v4.w, acc[c4 * 4 + 3]);
    }
  }
  float* op = ows + ((size_t)b * 256 + h * 32) * 3136 + m;
#pragma unroll
  for (int cc = 0; cc < 32; cc++) op[cc * 3136] = acc[cc] * inv;
}

// ---------------------------------------------------------------------------
extern "C" void kernel_launch(void* const* d_in, const int* in_sizes, int n_in,
                              void* d_out, int out_size, void* d_ws,
                              size_t ws_size, hipStream_t stream) {
  const float* x       = (const float*)d_in[0];
  const float* patch_w = (const float*)d_in[1];
  const float* patch_b = (const float*)d_in[2];
  const float* ln1_g   = (const float*)d_in[3];
  const float* ln1_b   = (const float*)d_in[4];
  const float* wq      = (const float*)d_in[5];
  const float* bq      = (const float*)d_in[6];
  const float* wk      = (const float*)d_in[7];
  const float* bk      = (const float*)d_in[8];
  const float* wv      = (const float*)d_in[9];
  const float* bv      = (const float*)d_in[10];
  const float* wo      = (const float*)d_in[11];
  const float* bo      = (const float*)d_in[12];
  const float* off_dw_w = (const float*)d_in[13];
  const float* off_dw_b = (const float*)d_in[14];
  const float* off_ln_g = (const float*)d_in[15];
  const float* off_ln_b = (const float*)d_in[16];
  const float* off_pw_w = (const float*)d_in[17];
  const float* rpe_w1  = (const float*)d_in[18];
  const float* rpe_b1  = (const float*)d_in[19];
  const float* rpe_w2  = (const float*)d_in[20];

  float* ws = (float*)d_ws;
  float* feat = ws + OFF_FEAT;
  float* q    = ws + OFF_Q;
  float* posw = ws + OFF_POS;
  float* xs   = ws + OFF_XS;
  float* kk   = ws + OFF_K;
  float* vv   = ws + OFF_V;
  float* attn_out = ws + OFF_FEAT;   // alias feat (dead after sampling)

  float* y = (float*)d_out;
  float* out_pos = y + 6422528;
  float* out_ref = out_pos + 4096;

  // A: patch embed + LN
  hipLaunchKernelGGL(k_patch_ln, dim3(3136), dim3(256), 0, stream,
                     x, patch_w, patch_b, ln1_g, ln1_b, feat);
  // B: q = wq @ feat + bq
  hipLaunchKernelGGL(k_gemm256, dim3(1568), dim3(256), 0, stream,
                     feat, wq, bq, q);
  // C: offset network -> pos (+ outputs pos, ref)
  hipLaunchKernelGGL(k_offset, dim3(16, 32), dim3(256), 0, stream,
                     q, off_dw_w, off_dw_b, off_ln_g, off_ln_b, off_pw_w,
                     posw, out_pos, out_ref);
  // D: bilinear sampling
  hipLaunchKernelGGL(k_sample, dim3(16, 32), dim3(256), 0, stream,
                     feat, posw, xs);
  // E: k, v projections
  hipLaunchKernelGGL(k_kv, dim3(64, 8), dim3(256), 0, stream,
                     xs, wk, bk, wv, bv, kk, vv);
  // F: attention (writes attn_out, aliases feat region)
  hipLaunchKernelGGL(k_attn, dim3(13, 64), dim3(256), 0, stream,
                     q, kk, vv, posw, rpe_w1, rpe_b1, rpe_w2, attn_out);
  // G: y = wo @ attn_out + bo
  hipLaunchKernelGGL(k_gemm256, dim3(1568), dim3(256), 0, stream,
                     attn_out, wo, bo, y);
}

// Round 2
// 583.855 us; speedup vs baseline: 1.7118x; 1.7118x over previous
//
#include <hip/hip_runtime.h>
#include <cstddef>

// Problem constants
// B=8, DIM=256, NH=8, H=W=56, G=4, CG=64, GH=2, HC=32, Hk=Wk=8, ns=64

// ws float offsets
#define OFF_FEAT 0u            // 6422528 floats (reused as attention-out after sampling)
#define OFF_Q    6422528u      // 6422528
#define OFF_POS  12845056u     // 4096
#define OFF_XS   12849152u     // 131072 (also aliased as offset-conv scratch earlier)
#define OFF_K    12980224u     // 131072
#define OFF_V    13111296u     // 131072

// ---------------------------------------------------------------------------
// Kernel A: patch embedding conv (3->256, 8x8, stride 8) + bias + LayerNorm over channels
__global__ __launch_bounds__(256) void k_patch_ln(
    const float* __restrict__ x, const float* __restrict__ pw,
    const float* __restrict__ pb, const float* __restrict__ g1,
    const float* __restrict__ b1, float* __restrict__ feat) {
  const int t = threadIdx.x;
  const int P0 = blockIdx.x * 8;           // flat position, 25088 total
  const int b = P0 / 3136;
  const int rem = P0 % 3136;
  const int oh = rem / 56;
  const int ow0 = rem % 56;                // multiple of 8

  __shared__ float sx[24 * 64];            // [ci*8+i][64 cols]
  for (int idx = t; idx < 24 * 64; idx += 256) {
    int rr = idx >> 6, cc = idx & 63;
    int ci = rr >> 3, i = rr & 7;
    sx[idx] = x[(((size_t)b * 3 + ci) * 448 + (oh * 8 + i)) * 448 + ow0 * 8 + cc];
  }
  __syncthreads();

  float acc[8];
#pragma unroll
  for (int p = 0; p < 8; p++) acc[p] = 0.f;
  const float* wrow = pw + t * 192;
  for (int r = 0; r < 192; r++) {
    float w = wrow[r];
    const float* s = &sx[(r >> 3) * 64 + (r & 7)];
#pragma unroll
    for (int p = 0; p < 8; p++) acc[p] = fmaf(w, s[p * 8], acc[p]);
  }
  float bias = pb[t];

  __shared__ float cv[8][257];
#pragma unroll
  for (int p = 0; p < 8; p++) cv[p][t] = acc[p] + bias;
  __syncthreads();

  // LN reduce: 32 threads per position
  int p = t >> 5, lane = t & 31;
  float s1 = 0.f, s2 = 0.f;
#pragma unroll
  for (int k = 0; k < 8; k++) {
    float v = cv[p][lane + k * 32];
    s1 += v; s2 += v * v;
  }
#pragma unroll
  for (int off = 16; off >= 1; off >>= 1) {
    s1 += __shfl_xor(s1, off);
    s2 += __shfl_xor(s2, off);
  }
  __shared__ float mean_s[8], rstd_s[8];
  if (lane == 0) {
    float m = s1 * (1.f / 256.f);
    float var = s2 * (1.f / 256.f) - m * m;
    mean_s[p] = m;
    rstd_s[p] = rsqrtf(var + 1e-5f);
  }
  __syncthreads();
  float gg = g1[t], bb = b1[t];
  size_t base = ((size_t)b * 256 + t) * 3136 + oh * 56 + ow0;
#pragma unroll
  for (int q = 0; q < 8; q++)
    feat[base + q] = (cv[q][t] - mean_s[q]) * rstd_s[q] * gg + bb;
}

// ---------------------------------------------------------------------------
// Kernel B: out[b,o,m] = sum_c w[o,c]*in[b,c,m] + bias[o]  (256x256, 25088 positions)
__global__ __launch_bounds__(256) void k_gemm256(
    const float* __restrict__ in, const float* __restrict__ w,
    const float* __restrict__ bias, float* __restrict__ out) {
  const int t = threadIdx.x;
  const int P0 = blockIdx.x * 16;
  const int b = P0 / 3136;
  const int m0 = P0 % 3136;

  __shared__ float si[256][16];
  {
    const float4* src = (const float4*)(in + ((size_t)b * 256 + t) * 3136 + m0);
    float4 a0 = src[0], a1 = src[1], a2 = src[2], a3 = src[3];
    float* d = si[t];
    *(float4*)(d + 0) = a0; *(float4*)(d + 4) = a1;
    *(float4*)(d + 8) = a2; *(float4*)(d + 12) = a3;
  }
  __syncthreads();

  float acc[16];
  float bv = bias[t];
#pragma unroll
  for (int j = 0; j < 16; j++) acc[j] = bv;
  const float* wr = w + t * 256;
  for (int c = 0; c < 256; c++) {
    float wv = wr[c];
    const float* s = si[c];
#pragma unroll
    for (int j = 0; j < 16; j++) acc[j] = fmaf(wv, s[j], acc[j]);
  }
  float* op = out + ((size_t)b * 256 + t) * 3136 + m0;
#pragma unroll
  for (int j = 0; j < 16; j++) op[j] = acc[j];
}

// ---------------------------------------------------------------------------
// Kernel C1: offset depthwise conv (28x28, stride 8, pad 14), one wave per
// (bg, channel). Channel plane staged in LDS with zero halo + bank swizzle.
// Layout addr(r,c) = r*84 + c + (r>>3): lanes (oh,ow) -> bank 8*ow+oh mod 32,
// exactly 2 lanes/bank (free). No __syncthreads needed: each wave owns a plane.
__global__ __launch_bounds__(128) void k_offset_conv(
    const float* __restrict__ q, const float* __restrict__ dww,
    float* __restrict__ convo) {
  const int bg = blockIdx.y;               // 0..31
  const int wv = threadIdx.x >> 6;         // 0..1
  const int lane = threadIdx.x & 63;
  const int ch = blockIdx.x * 2 + wv;      // 0..63
  const int b = bg >> 2, g = bg & 3;

  __shared__ float pl[2][7072];
  float* P = pl[wv];
  for (int idx = lane; idx < 7072; idx += 64) P[idx] = 0.f;

  const float* qb = q + ((size_t)b * 256 + g * 64 + ch) * 3136;
  if (lane < 56) {
    for (int r = 0; r < 56; r++) {
      int hr = r + 14;
      P[hr * 84 + (lane + 14) + (hr >> 3)] = qb[r * 56 + lane];
    }
  }
  // same-wave DS ops are program-ordered; compute reads only this wave's plane

  const int oh = lane >> 3, ow = lane & 7;
  const int chs = __builtin_amdgcn_readfirstlane(ch);
  const float* wr = dww + (size_t)chs * 784;
  float acc = 0.f;
  const int r0 = oh * 8, c0 = ow * 8;
  for (int i = 0; i < 28; i++) {
    int hr = r0 + i;
    const float* prow = P + hr * 84 + c0 + (hr >> 3);
    const float* wrr = wr + i * 28;
#pragma unroll
    for (int j = 0; j < 28; j++)
      acc = fmaf(prow[j], wrr[j], acc);
  }
  // store as [bg][pos][ch] for coalesced reads in the post kernel
  convo[bg * 4096 + lane * 64 + ch] = acc;
}

// ---------------------------------------------------------------------------
// Kernel C2: LN(64) + GELU + pointwise(2x64) + tanh + reference points.
// One wave (lane = channel) per output position.
__global__ __launch_bounds__(256) void k_offset_post(
    const float* __restrict__ convo, const float* __restrict__ dwb,
    const float* __restrict__ lng, const float* __restrict__ lnb,
    const float* __restrict__ pww, float* __restrict__ pos_ws,
    float* __restrict__ out_pos, float* __restrict__ out_ref) {
  const int bg = blockIdx.y;               // 0..31
  const int wv = threadIdx.x >> 6;         // 0..3
  const int lane = threadIdx.x & 63;       // cg
  const int idx = blockIdx.x * 4 + wv;     // 0..63
  const int oh = idx >> 3, ow = idx & 7;

  float acc = convo[bg * 4096 + idx * 64 + lane] + dwb[lane];

  // LN over 64 lanes
  float s1 = acc, s2 = acc * acc;
#pragma unroll
  for (int off = 32; off >= 1; off >>= 1) {
    s1 += __shfl_xor(s1, off);
    s2 += __shfl_xor(s2, off);
  }
  float m = s1 * (1.f / 64.f);
  float var = s2 * (1.f / 64.f) - m * m;
  float val = (acc - m) * rsqrtf(var + 1e-5f) * lng[lane] + lnb[lane];
  val = 0.5f * val * (1.f + erff(val * 0.70710678118654752f));
  float p0 = pww[lane] * val, p1 = pww[64 + lane] * val;
#pragma unroll
  for (int off = 32; off >= 1; off >>= 1) {
    p0 += __shfl_xor(p0, off);
    p1 += __shfl_xor(p1, off);
  }
  if (lane == 0) {
    float offy = tanhf(p0) * (2.0f / 7.0f);
    float offx = tanhf(p1) * (2.0f / 7.0f);
    float ry = (0.5f + oh) * (2.0f / 7.0f) - 1.0f;
    float rx = (0.5f + ow) * (2.0f / 7.0f) - 1.0f;
    float py = offy + ry, px = offx + rx;
    int o = bg * 128 + idx * 2;
    pos_ws[o] = py;  pos_ws[o + 1] = px;
    out_pos[o] = py; out_pos[o + 1] = px;
    out_ref[o] = ry; out_ref[o + 1] = rx;
  }
}

// ---------------------------------------------------------------------------
// Kernel D: bilinear sampling. One wave (64 group-channels) per sample point.
__global__ __launch_bounds__(256) void k_sample(
    const float* __restrict__ feat, const float* __restrict__ pos_ws,
    float* __restrict__ xs) {
  const int bg = blockIdx.y;
  const int wv = threadIdx.x >> 6, lane = threadIdx.x & 63;
  const int n = blockIdx.x * 4 + wv;
  const int b = bg >> 2, g = bg & 3;

  float py = pos_ws[bg * 128 + n * 2];
  float px = pos_ws[bg * 128 + n * 2 + 1];
  float gx = (px + 1.f) * 0.5f * 55.f;
  float gy = (py + 1.f) * 0.5f * 55.f;
  float x0f = floorf(gx), y0f = floorf(gy);
  int x0 = (int)x0f, y0 = (int)y0f;
  float wx1 = gx - x0f, wx0 = 1.f - wx1;
  float wy1 = gy - y0f, wy0 = 1.f - wy1;

  const float* fb = feat + ((size_t)b * 256 + g * 64 + lane) * 3136;
  float acc = 0.f;
  if (x0 >= 0 && x0 <= 55 && y0 >= 0 && y0 <= 55)       acc = fmaf(fb[y0 * 56 + x0],           wx0 * wy0, acc);
  if (x0 + 1 >= 0 && x0 + 1 <= 55 && y0 >= 0 && y0 <= 55)   acc = fmaf(fb[y0 * 56 + x0 + 1],       wx1 * wy0, acc);
  if (x0 >= 0 && x0 <= 55 && y0 + 1 >= 0 && y0 + 1 <= 55)   acc = fmaf(fb[(y0 + 1) * 56 + x0],     wx0 * wy1, acc);
  if (x0 + 1 >= 0 && x0 + 1 <= 55 && y0 + 1 >= 0 && y0 + 1 <= 55) acc = fmaf(fb[(y0 + 1) * 56 + x0 + 1], wx1 * wy1, acc);

  xs[((size_t)bg * 64 + lane) * 64 + n] = acc;
}

// ---------------------------------------------------------------------------
// Kernel E: k,v projections on sampled features. One block per (b, n).
__global__ __launch_bounds__(256) void k_kv(
    const float* __restrict__ xs, const float* __restrict__ wk,
    const float* __restrict__ bk, const float* __restrict__ wv_,
    const float* __restrict__ bv, float* __restrict__ ko,
    float* __restrict__ vo) {
  const int b = blockIdx.y;   // 0..7
  const int n = blockIdx.x;   // 0..63
  const int t = threadIdx.x;
  __shared__ float sxs[256];
  sxs[t] = xs[((size_t)b * 256 + t) * 64 + n];
  __syncthreads();
  float ak = bk[t], av = bv[t];
  const float* wkr = wk + t * 256;
  const float* wvr = wv_ + t * 256;
  for (int c = 0; c < 256; c++) {
    float xv = sxs[c];
    ak = fmaf(wkr[c], xv, ak);
    av = fmaf(wvr[c], xv, av);
  }
  ko[((size_t)b * 256 + t) * 64 + n] = ak;
  vo[((size_t)b * 256 + t) * 64 + n] = av;
}

// ---------------------------------------------------------------------------
// Kernel F: attention. One thread per query; K/V/pos/rpe staged in LDS.
__global__ __launch_bounds__(256) void k_attn(
    const float* __restrict__ qws, const float* __restrict__ kws,
    const float* __restrict__ vws, const float* __restrict__ pos_ws,
    const float* __restrict__ w1, const float* __restrict__ b1,
    const float* __restrict__ w2, float* __restrict__ ows) {
  const int bh = blockIdx.y;          // 0..63
  const int b = bh >> 3, h = bh & 7;
  const int g = h >> 1, gh = h & 1;
  const int bg = b * 4 + g;
  const int t = threadIdx.x;

  __shared__ float Kt[64][36];        // [n][cc], padded
  __shared__ float Vt[64][36];
  __shared__ float posl[128];
  __shared__ float rpe4[32][4];       // {w1y, w1x, b1, w2[gh]}

  const float* kp = kws + ((size_t)b * 256 + h * 32) * 64;
  const float* vp = vws + ((size_t)b * 256 + h * 32) * 64;
  for (int i = t; i < 2048; i += 256) {
    int cc = i >> 6, n = i & 63;
    Kt[n][cc] = kp[i];
    Vt[n][cc] = vp[i];
  }
  if (t < 128) posl[t] = pos_ws[bg * 128 + t];
  if (t < 32) {
    rpe4[t][0] = w1[t * 2];
    rpe4[t][1] = w1[t * 2 + 1];
    rpe4[t][2] = b1[t];
    rpe4[t][3] = w2[gh * 32 + t];
  }
  __syncthreads();

  const int m = blockIdx.x * 256 + t;
  if (m >= 3136) return;
  const int my = m / 56, mx = m % 56;
  const float qgy = ((float)my * (56.0f / 55.0f)) * (2.0f / 55.0f) - 1.0f;
  const float qgx = ((float)mx * (56.0f / 55.0f)) * (2.0f / 55.0f) - 1.0f;

  float qv[32];
  const float* qp = qws + ((size_t)b * 256 + h * 32) * 3136 + m;
#pragma unroll
  for (int cc = 0; cc < 32; cc++) qv[cc] = qp[cc * 3136];

  const float scale = 0.17677669529663687f;  // 1/sqrt(32)
  float p[64];
  float mmax = -1e30f;
#pragma unroll
  for (int n = 0; n < 64; n++) {
    float s = 0.f;
    const float4* kk = (const float4*)Kt[n];
#pragma unroll
    for (int c4 = 0; c4 < 8; c4++) {
      float4 kv = kk[c4];
      s = fmaf(qv[c4 * 4 + 0], kv.x, s);
      s = fmaf(qv[c4 * 4 + 1], kv.y, s);
      s = fmaf(qv[c4 * 4 + 2], kv.z, s);
      s = fmaf(qv[c4 * 4 + 3], kv.w, s);
    }
    s *= scale;
    float dy = (qgy - posl[n * 2]) * 4.f;
    float dx = (qgx - posl[n * 2 + 1]) * 4.f;
    float ty = copysignf(log2f(fabsf(dy) + 1.f) * (1.f / 3.f), dy);
    float tx = copysignf(log2f(fabsf(dx) + 1.f) * (1.f / 3.f), dx);
    float biasv = 0.f;
#pragma unroll
    for (int j = 0; j < 32; j++) {
      float4 r = *(const float4*)rpe4[j];
      float hv = fmaf(r.x, ty, fmaf(r.y, tx, r.z));
      hv = fmaxf(hv, 0.f);
      biasv = fmaf(r.w, hv, biasv);
    }
    s += biasv;
    p[n] = s;
    mmax = fmaxf(mmax, s);
  }
  float sum = 0.f;
#pragma unroll
  for (int n = 0; n < 64; n++) {
    float e = __expf(p[n] - mmax);
    p[n] = e;
    sum += e;
  }
  float inv = 1.f / sum;

  float acc[32];
#pragma unroll
  for (int cc = 0; cc < 32; cc++) acc[cc] = 0.f;
#pragma unroll
  for (int n = 0; n < 64; n++) {
    float pw_ = p[n];
    const float4* vv = (const float4*)Vt[n];
#pragma unroll
    for (int c4 = 0; c4 < 8; c4++) {
      float4 v4 = vv[c4];
      acc[c4 * 4 + 0] = fmaf(pw_, v4.x, acc[c4 * 4 + 0]);
      acc[c4 * 4 + 1] = fmaf(pw_, v4.y, acc[c4 * 4 + 1]);
      acc[c4 * 4 + 2] = fmaf(pw_, v4.z, acc[c4 * 4 + 2]);
      acc[c4 * 4 + 3] = fmaf(pw_, v4.w, acc[c4 * 4 + 3]);
    }
  }
  float* op = ows + ((size_t)b * 256 + h * 32) * 3136 + m;
#pragma unroll
  for (int cc = 0; cc < 32; cc++) op[cc * 3136] = acc[cc] * inv;
}

// ---------------------------------------------------------------------------
extern "C" void kernel_launch(void* const* d_in, const int* in_sizes, int n_in,
                              void* d_out, int out_size, void* d_ws,
                              size_t ws_size, hipStream_t stream) {
  const float* x       = (const float*)d_in[0];
  const float* patch_w = (const float*)d_in[1];
  const float* patch_b = (const float*)d_in[2];
  const float* ln1_g   = (const float*)d_in[3];
  const float* ln1_b   = (const float*)d_in[4];
  const float* wq      = (const float*)d_in[5];
  const float* bq      = (const float*)d_in[6];
  const float* wk      = (const float*)d_in[7];
  const float* bk      = (const float*)d_in[8];
  const float* wv      = (const float*)d_in[9];
  const float* bv      = (const float*)d_in[10];
  const float* wo      = (const float*)d_in[11];
  const float* bo      = (const float*)d_in[12];
  const float* off_dw_w = (const float*)d_in[13];
  const float* off_dw_b = (const float*)d_in[14];
  const float* off_ln_g = (const float*)d_in[15];
  const float* off_ln_b = (const float*)d_in[16];
  const float* off_pw_w = (const float*)d_in[17];
  const float* rpe_w1  = (const float*)d_in[18];
  const float* rpe_b1  = (const float*)d_in[19];
  const float* rpe_w2  = (const float*)d_in[20];

  float* ws = (float*)d_ws;
  float* feat = ws + OFF_FEAT;
  float* q    = ws + OFF_Q;
  float* posw = ws + OFF_POS;
  float* xs   = ws + OFF_XS;
  float* kk   = ws + OFF_K;
  float* vv   = ws + OFF_V;
  float* attn_out = ws + OFF_FEAT;   // alias feat (dead after sampling)
  float* convo = ws + OFF_XS;        // alias xs (convo dead before xs written)

  float* y = (float*)d_out;
  float* out_pos = y + 6422528;
  float* out_ref = out_pos + 4096;

  // A: patch embed + LN
  hipLaunchKernelGGL(k_patch_ln, dim3(3136), dim3(256), 0, stream,
                     x, patch_w, patch_b, ln1_g, ln1_b, feat);
  // B: q = wq @ feat + bq
  hipLaunchKernelGGL(k_gemm256, dim3(1568), dim3(256), 0, stream,
                     feat, wq, bq, q);
  // C1: offset depthwise conv
  hipLaunchKernelGGL(k_offset_conv, dim3(32, 32), dim3(128), 0, stream,
                     q, off_dw_w, convo);
  // C2: offset post (LN + GELU + pointwise + tanh) -> pos
  hipLaunchKernelGGL(k_offset_post, dim3(16, 32), dim3(256), 0, stream,
                     convo, off_dw_b, off_ln_g, off_ln_b, off_pw_w,
                     posw, out_pos, out_ref);
  // D: bilinear sampling
  hipLaunchKernelGGL(k_sample, dim3(16, 32), dim3(256), 0, stream,
                     feat, posw, xs);
  // E: k, v projections
  hipLaunchKernelGGL(k_kv, dim3(64, 8), dim3(256), 0, stream,
                     xs, wk, bk, wv, bv, kk, vv);
  // F: attention (writes attn_out, aliases feat region)
  hipLaunchKernelGGL(k_attn, dim3(13, 64), dim3(256), 0, stream,
                     q, kk, vv, posw, rpe_w1, rpe_b1, rpe_w2, attn_out);
  // G: y = wo @ attn_out + bo
  hipLaunchKernelGGL(k_gemm256, dim3(1568), dim3(256), 0, stream,
                     attn_out, wo, bo, y);
}

// Round 3
// 463.677 us; speedup vs baseline: 2.1555x; 1.2592x over previous
//
#include <hip/hip_runtime.h>
#include <cstddef>

// Problem constants
// B=8, DIM=256, NH=8, H=W=56, G=4, CG=64, GH=2, HC=32, Hk=Wk=8, ns=64

// ws float offsets
#define OFF_FEAT 0u            // 6422528 floats (reused as attention-out after sampling)
#define OFF_Q    6422528u      // 6422528
#define OFF_POS  12845056u     // 4096
#define OFF_XS   12849152u     // 131072 (also aliased as offset-conv scratch earlier)
#define OFF_K    12980224u     // 131072
#define OFF_V    13111296u     // 131072
#define OFF_PWT  13242368u     // 49152  (pwT [192][256])
#define OFF_WQT  13291520u     // 65536  (wqT [c][o])
#define OFF_WKT  13357056u     // 65536
#define OFF_WVT  13422592u     // 65536
#define OFF_WOT  13488128u     // 65536  -> end 13553664 floats (54.2 MB)

// ---------------------------------------------------------------------------
// Kernel T: transpose weights for coalesced per-lane access.
// grid (256, 5): y=0 -> patch weights [oc][192] -> [r][256]; y=1..4 -> 256x256.
__global__ __launch_bounds__(256) void k_wtrans(
    const float* __restrict__ pw, const float* __restrict__ wq,
    const float* __restrict__ wk, const float* __restrict__ wv,
    const float* __restrict__ wo, float* __restrict__ pwT,
    float* __restrict__ wqT, float* __restrict__ wkT,
    float* __restrict__ wvT, float* __restrict__ woT) {
  const int o = blockIdx.x;     // row (coalesced read dim)
  const int t = threadIdx.x;
  const int m = blockIdx.y;
  if (m == 0) {
    if (t < 192) pwT[t * 256 + o] = pw[o * 192 + t];
  } else {
    const float* in = (m == 1) ? wq : (m == 2) ? wk : (m == 3) ? wv : wo;
    float* out = (m == 1) ? wqT : (m == 2) ? wkT : (m == 3) ? wvT : woT;
    out[t * 256 + o] = in[o * 256 + t];
  }
}

// ---------------------------------------------------------------------------
// Kernel A: patch embedding conv (3->256, 8x8, stride 8) + bias + LayerNorm.
// 28 positions/block (one half-row), im2col staged as [r][28] in LDS so the
// inner loop is broadcast ds_read_b128 + coalesced weight load (pwT).
__global__ __launch_bounds__(256) void k_patch_ln(
    const float* __restrict__ x, const float* __restrict__ pwT,
    const float* __restrict__ pb, const float* __restrict__ g1,
    const float* __restrict__ b1, float* __restrict__ feat) {
  const int t = threadIdx.x;
  const int P0 = blockIdx.x * 28;
  const int b = P0 / 3136;
  const int rem = P0 % 3136;
  const int oh = rem / 56;
  const int ow0 = rem % 56;    // 0 or 28

  __shared__ float smem[7252];           // union: sx2[192*28] | cv[28*257]; +mean/rstd
  float* sx2 = smem;
  float* mean_s = smem + 7196;
  float* rstd_s = smem + 7224;

  // stage im2col: X[r][p], r = ci*64 + i*8 + j, p = 0..27
  for (int idx = t; idx < 5376; idx += 256) {
    int ci = idx / 1792;
    int rem2 = idx - ci * 1792;
    int i = rem2 / 224;
    int cc = rem2 - i * 224;
    int r = ci * 64 + i * 8 + (cc & 7);
    int p = cc >> 3;
    sx2[r * 28 + p] =
        x[(((size_t)b * 3 + ci) * 448 + (oh * 8 + i)) * 448 + ow0 * 8 + cc];
  }
  __syncthreads();

  float acc[28];
#pragma unroll
  for (int p = 0; p < 28; p++) acc[p] = 0.f;
  for (int r = 0; r < 192; r++) {
    float w = pwT[r * 256 + t];          // coalesced across lanes
    const float* s = &sx2[r * 28];       // broadcast b128 reads
#pragma unroll
    for (int p = 0; p < 28; p++) acc[p] = fmaf(w, s[p], acc[p]);
  }
  float bias = pb[t];
  __syncthreads();                       // all sx2 reads done before cv overwrite

  float* cv = smem;                      // [28][257]
#pragma unroll
  for (int p = 0; p < 28; p++) cv[p * 257 + t] = acc[p] + bias;
  __syncthreads();

  // LN over 256 channels: 8 groups of 32 lanes, each group handles p, p+8, ...
  int lane = t & 31;
  for (int p = t >> 5; p < 28; p += 8) {
    float s1 = 0.f, s2 = 0.f;
#pragma unroll
    for (int k = 0; k < 8; k++) {
      float v = cv[p * 257 + lane + k * 32];
      s1 += v; s2 += v * v;
    }
#pragma unroll
    for (int off = 16; off >= 1; off >>= 1) {
      s1 += __shfl_xor(s1, off);
      s2 += __shfl_xor(s2, off);
    }
    if (lane == 0) {
      float m = s1 * (1.f / 256.f);
      float var = s2 * (1.f / 256.f) - m * m;
      mean_s[p] = m;
      rstd_s[p] = rsqrtf(var + 1e-5f);
    }
  }
  __syncthreads();
  float gg = g1[t], bb = b1[t];
  size_t base = ((size_t)b * 256 + t) * 3136 + oh * 56 + ow0;
#pragma unroll
  for (int p = 0; p < 28; p++)
    feat[base + p] = (cv[p * 257 + t] - mean_s[p]) * rstd_s[p] * gg + bb;
}

// ---------------------------------------------------------------------------
// Kernel B: out[b,o,m] = sum_c wT[c,o]*in[b,c,m] + bias[o]
__global__ __launch_bounds__(256) void k_gemm256(
    const float* __restrict__ in, const float* __restrict__ wT,
    const float* __restrict__ bias, float* __restrict__ out) {
  const int t = threadIdx.x;
  const int P0 = blockIdx.x * 16;
  const int b = P0 / 3136;
  const int m0 = P0 % 3136;

  __shared__ float si[256][16];
  {
    const float4* src = (const float4*)(in + ((size_t)b * 256 + t) * 3136 + m0);
    float4 a0 = src[0], a1 = src[1], a2 = src[2], a3 = src[3];
    float* d = si[t];
    *(float4*)(d + 0) = a0; *(float4*)(d + 4) = a1;
    *(float4*)(d + 8) = a2; *(float4*)(d + 12) = a3;
  }
  __syncthreads();

  float acc[16];
  float bv = bias[t];
#pragma unroll
  for (int j = 0; j < 16; j++) acc[j] = bv;
  for (int c = 0; c < 256; c++) {
    float wv = wT[c * 256 + t];          // coalesced across lanes
    const float* s = si[c];
#pragma unroll
    for (int j = 0; j < 16; j++) acc[j] = fmaf(wv, s[j], acc[j]);
  }
  float* op = out + ((size_t)b * 256 + t) * 3136 + m0;
#pragma unroll
  for (int j = 0; j < 16; j++) op[j] = acc[j];
}

// ---------------------------------------------------------------------------
// Kernel C1: offset depthwise conv (28x28, stride 8, pad 14), one wave per
// (bg, channel). Channel plane staged in LDS with zero halo + bank swizzle.
__global__ __launch_bounds__(128) void k_offset_conv(
    const float* __restrict__ q, const float* __restrict__ dww,
    float* __restrict__ convo) {
  const int bg = blockIdx.y;               // 0..31
  const int wv = threadIdx.x >> 6;         // 0..1
  const int lane = threadIdx.x & 63;
  const int ch = blockIdx.x * 2 + wv;      // 0..63
  const int b = bg >> 2, g = bg & 3;

  __shared__ float pl[2][7072];
  float* P = pl[wv];
  for (int idx = lane; idx < 7072; idx += 64) P[idx] = 0.f;

  const float* qb = q + ((size_t)b * 256 + g * 64 + ch) * 3136;
  if (lane < 56) {
    for (int r = 0; r < 56; r++) {
      int hr = r + 14;
      P[hr * 84 + (lane + 14) + (hr >> 3)] = qb[r * 56 + lane];
    }
  }
  // same-wave DS ops are program-ordered; compute reads only this wave's plane

  const int oh = lane >> 3, ow = lane & 7;
  const int chs = __builtin_amdgcn_readfirstlane(ch);
  const float* wr = dww + (size_t)chs * 784;
  float acc = 0.f;
  const int r0 = oh * 8, c0 = ow * 8;
  for (int i = 0; i < 28; i++) {
    int hr = r0 + i;
    const float* prow = P + hr * 84 + c0 + (hr >> 3);
    const float* wrr = wr + i * 28;
#pragma unroll
    for (int j = 0; j < 28; j++)
      acc = fmaf(prow[j], wrr[j], acc);
  }
  convo[bg * 4096 + lane * 64 + ch] = acc;
}

// ---------------------------------------------------------------------------
// Kernel C2: LN(64) + GELU + pointwise(2x64) + tanh + reference points.
__global__ __launch_bounds__(256) void k_offset_post(
    const float* __restrict__ convo, const float* __restrict__ dwb,
    const float* __restrict__ lng, const float* __restrict__ lnb,
    const float* __restrict__ pww, float* __restrict__ pos_ws,
    float* __restrict__ out_pos, float* __restrict__ out_ref) {
  const int bg = blockIdx.y;               // 0..31
  const int wv = threadIdx.x >> 6;         // 0..3
  const int lane = threadIdx.x & 63;       // cg
  const int idx = blockIdx.x * 4 + wv;     // 0..63
  const int oh = idx >> 3, ow = idx & 7;

  float acc = convo[bg * 4096 + idx * 64 + lane] + dwb[lane];

  float s1 = acc, s2 = acc * acc;
#pragma unroll
  for (int off = 32; off >= 1; off >>= 1) {
    s1 += __shfl_xor(s1, off);
    s2 += __shfl_xor(s2, off);
  }
  float m = s1 * (1.f / 64.f);
  float var = s2 * (1.f / 64.f) - m * m;
  float val = (acc - m) * rsqrtf(var + 1e-5f) * lng[lane] + lnb[lane];
  val = 0.5f * val * (1.f + erff(val * 0.70710678118654752f));
  float p0 = pww[lane] * val, p1 = pww[64 + lane] * val;
#pragma unroll
  for (int off = 32; off >= 1; off >>= 1) {
    p0 += __shfl_xor(p0, off);
    p1 += __shfl_xor(p1, off);
  }
  if (lane == 0) {
    float offy = tanhf(p0) * (2.0f / 7.0f);
    float offx = tanhf(p1) * (2.0f / 7.0f);
    float ry = (0.5f + oh) * (2.0f / 7.0f) - 1.0f;
    float rx = (0.5f + ow) * (2.0f / 7.0f) - 1.0f;
    float py = offy + ry, px = offx + rx;
    int o = bg * 128 + idx * 2;
    pos_ws[o] = py;  pos_ws[o + 1] = px;
    out_pos[o] = py; out_pos[o + 1] = px;
    out_ref[o] = ry; out_ref[o + 1] = rx;
  }
}

// ---------------------------------------------------------------------------
// Kernel D: bilinear sampling. One wave (64 group-channels) per sample point.
__global__ __launch_bounds__(256) void k_sample(
    const float* __restrict__ feat, const float* __restrict__ pos_ws,
    float* __restrict__ xs) {
  const int bg = blockIdx.y;
  const int wv = threadIdx.x >> 6, lane = threadIdx.x & 63;
  const int n = blockIdx.x * 4 + wv;
  const int b = bg >> 2, g = bg & 3;

  float py = pos_ws[bg * 128 + n * 2];
  float px = pos_ws[bg * 128 + n * 2 + 1];
  float gx = (px + 1.f) * 0.5f * 55.f;
  float gy = (py + 1.f) * 0.5f * 55.f;
  float x0f = floorf(gx), y0f = floorf(gy);
  int x0 = (int)x0f, y0 = (int)y0f;
  float wx1 = gx - x0f, wx0 = 1.f - wx1;
  float wy1 = gy - y0f, wy0 = 1.f - wy1;

  const float* fb = feat + ((size_t)b * 256 + g * 64 + lane) * 3136;
  float acc = 0.f;
  if (x0 >= 0 && x0 <= 55 && y0 >= 0 && y0 <= 55)       acc = fmaf(fb[y0 * 56 + x0],           wx0 * wy0, acc);
  if (x0 + 1 >= 0 && x0 + 1 <= 55 && y0 >= 0 && y0 <= 55)   acc = fmaf(fb[y0 * 56 + x0 + 1],       wx1 * wy0, acc);
  if (x0 >= 0 && x0 <= 55 && y0 + 1 >= 0 && y0 + 1 <= 55)   acc = fmaf(fb[(y0 + 1) * 56 + x0],     wx0 * wy1, acc);
  if (x0 + 1 >= 0 && x0 + 1 <= 55 && y0 + 1 >= 0 && y0 + 1 <= 55) acc = fmaf(fb[(y0 + 1) * 56 + x0 + 1], wx1 * wy1, acc);

  xs[((size_t)bg * 64 + lane) * 64 + n] = acc;
}

// ---------------------------------------------------------------------------
// Kernel E: k,v projections on sampled features. One block per (b, n).
__global__ __launch_bounds__(256) void k_kv(
    const float* __restrict__ xs, const float* __restrict__ wkT,
    const float* __restrict__ bk, const float* __restrict__ wvT,
    const float* __restrict__ bv, float* __restrict__ ko,
    float* __restrict__ vo) {
  const int b = blockIdx.y;   // 0..7
  const int n = blockIdx.x;   // 0..63
  const int t = threadIdx.x;
  __shared__ float sxs[256];
  sxs[t] = xs[((size_t)b * 256 + t) * 64 + n];
  __syncthreads();
  float ak = bk[t], av = bv[t];
  for (int c = 0; c < 256; c++) {
    float xv = sxs[c];
    ak = fmaf(wkT[c * 256 + t], xv, ak);
    av = fmaf(wvT[c * 256 + t], xv, av);
  }
  ko[((size_t)b * 256 + t) * 64 + n] = ak;
  vo[((size_t)b * 256 + t) * 64 + n] = av;
}

// ---------------------------------------------------------------------------
// Kernel F: attention. One thread per query; K/V/pos/rpe staged in LDS.
__global__ __launch_bounds__(256) void k_attn(
    const float* __restrict__ qws, const float* __restrict__ kws,
    const float* __restrict__ vws, const float* __restrict__ pos_ws,
    const float* __restrict__ w1, const float* __restrict__ b1,
    const float* __restrict__ w2, float* __restrict__ ows) {
  const int bh = blockIdx.y;          // 0..63
  const int b = bh >> 3, h = bh & 7;
  const int g = h >> 1, gh = h & 1;
  const int bg = b * 4 + g;
  const int t = threadIdx.x;

  __shared__ float Kt[64][36];        // [n][cc], padded
  __shared__ float Vt[64][36];
  __shared__ float posl[128];
  __shared__ float rpe4[32][4];       // {w1y, w1x, b1, w2[gh]}

  const float* kp = kws + ((size_t)b * 256 + h * 32) * 64;
  const float* vp = vws + ((size_t)b * 256 + h * 32) * 64;
  for (int i = t; i < 2048; i += 256) {
    int cc = i >> 6, n = i & 63;
    Kt[n][cc] = kp[i];
    Vt[n][cc] = vp[i];
  }
  if (t < 128) posl[t] = pos_ws[bg * 128 + t];
  if (t < 32) {
    rpe4[t][0] = w1[t * 2];
    rpe4[t][1] = w1[t * 2 + 1];
    rpe4[t][2] = b1[t];
    rpe4[t][3] = w2[gh * 32 + t];
  }
  __syncthreads();

  const int m = blockIdx.x * 256 + t;
  if (m >= 3136) return;
  const int my = m / 56, mx = m % 56;
  const float qgy = ((float)my * (56.0f / 55.0f)) * (2.0f / 55.0f) - 1.0f;
  const float qgx = ((float)mx * (56.0f / 55.0f)) * (2.0f / 55.0f) - 1.0f;

  float qv[32];
  const float* qp = qws + ((size_t)b * 256 + h * 32) * 3136 + m;
#pragma unroll
  for (int cc = 0; cc < 32; cc++) qv[cc] = qp[cc * 3136];

  const float scale = 0.17677669529663687f;  // 1/sqrt(32)
  float p[64];
  float mmax = -1e30f;
#pragma unroll
  for (int n = 0; n < 64; n++) {
    float s = 0.f;
    const float4* kk = (const float4*)Kt[n];
#pragma unroll
    for (int c4 = 0; c4 < 8; c4++) {
      float4 kv = kk[c4];
      s = fmaf(qv[c4 * 4 + 0], kv.x, s);
      s = fmaf(qv[c4 * 4 + 1], kv.y, s);
      s = fmaf(qv[c4 * 4 + 2], kv.z, s);
      s = fmaf(qv[c4 * 4 + 3], kv.w, s);
    }
    s *= scale;
    float dy = (qgy - posl[n * 2]) * 4.f;
    float dx = (qgx - posl[n * 2 + 1]) * 4.f;
    float ty = copysignf(log2f(fabsf(dy) + 1.f) * (1.f / 3.f), dy);
    float tx = copysignf(log2f(fabsf(dx) + 1.f) * (1.f / 3.f), dx);
    float biasv = 0.f;
#pragma unroll
    for (int j = 0; j < 32; j++) {
      float4 r = *(const float4*)rpe4[j];
      float hv = fmaf(r.x, ty, fmaf(r.y, tx, r.z));
      hv = fmaxf(hv, 0.f);
      biasv = fmaf(r.w, hv, biasv);
    }
    s += biasv;
    p[n] = s;
    mmax = fmaxf(mmax, s);
  }
  float sum = 0.f;
#pragma unroll
  for (int n = 0; n < 64; n++) {
    float e = __expf(p[n] - mmax);
    p[n] = e;
    sum += e;
  }
  float inv = 1.f / sum;

  float acc[32];
#pragma unroll
  for (int cc = 0; cc < 32; cc++) acc[cc] = 0.f;
#pragma unroll
  for (int n = 0; n < 64; n++) {
    float pw_ = p[n];
    const float4* vv = (const float4*)Vt[n];
#pragma unroll
    for (int c4 = 0; c4 < 8; c4++) {
      float4 v4 = vv[c4];
      acc[c4 * 4 + 0] = fmaf(pw_, v4.x, acc[c4 * 4 + 0]);
      acc[c4 * 4 + 1] = fmaf(pw_, v4.y, acc[c4 * 4 + 1]);
      acc[c4 * 4 + 2] = fmaf(pw_, v4.z, acc[c4 * 4 + 2]);
      acc[c4 * 4 + 3] = fmaf(pw_, v4.w, acc[c4 * 4 + 3]);
    }
  }
  float* op = ows + ((size_t)b * 256 + h * 32) * 3136 + m;
#pragma unroll
  for (int cc = 0; cc < 32; cc++) op[cc * 3136] = acc[cc] * inv;
}

// ---------------------------------------------------------------------------
extern "C" void kernel_launch(void* const* d_in, const int* in_sizes, int n_in,
                              void* d_out, int out_size, void* d_ws,
                              size_t ws_size, hipStream_t stream) {
  const float* x       = (const float*)d_in[0];
  const float* patch_w = (const float*)d_in[1];
  const float* patch_b = (const float*)d_in[2];
  const float* ln1_g   = (const float*)d_in[3];
  const float* ln1_b   = (const float*)d_in[4];
  const float* wq      = (const float*)d_in[5];
  const float* bq      = (const float*)d_in[6];
  const float* wk      = (const float*)d_in[7];
  const float* bk      = (const float*)d_in[8];
  const float* wv      = (const float*)d_in[9];
  const float* bv      = (const float*)d_in[10];
  const float* wo      = (const float*)d_in[11];
  const float* bo      = (const float*)d_in[12];
  const float* off_dw_w = (const float*)d_in[13];
  const float* off_dw_b = (const float*)d_in[14];
  const float* off_ln_g = (const float*)d_in[15];
  const float* off_ln_b = (const float*)d_in[16];
  const float* off_pw_w = (const float*)d_in[17];
  const float* rpe_w1  = (const float*)d_in[18];
  const float* rpe_b1  = (const float*)d_in[19];
  const float* rpe_w2  = (const float*)d_in[20];

  float* ws = (float*)d_ws;
  float* feat = ws + OFF_FEAT;
  float* q    = ws + OFF_Q;
  float* posw = ws + OFF_POS;
  float* xs   = ws + OFF_XS;
  float* kk   = ws + OFF_K;
  float* vv   = ws + OFF_V;
  float* attn_out = ws + OFF_FEAT;   // alias feat (dead after sampling)
  float* convo = ws + OFF_XS;        // alias xs (convo dead before xs written)
  float* pwT  = ws + OFF_PWT;
  float* wqT  = ws + OFF_WQT;
  float* wkT  = ws + OFF_WKT;
  float* wvT  = ws + OFF_WVT;
  float* woT  = ws + OFF_WOT;

  float* y = (float*)d_out;
  float* out_pos = y + 6422528;
  float* out_ref = out_pos + 4096;

  // T: weight transposes
  hipLaunchKernelGGL(k_wtrans, dim3(256, 5), dim3(256), 0, stream,
                     patch_w, wq, wk, wv, wo, pwT, wqT, wkT, wvT, woT);
  // A: patch embed + LN
  hipLaunchKernelGGL(k_patch_ln, dim3(896), dim3(256), 0, stream,
                     x, pwT, patch_b, ln1_g, ln1_b, feat);
  // B: q = wq @ feat + bq
  hipLaunchKernelGGL(k_gemm256, dim3(1568), dim3(256), 0, stream,
                     feat, wqT, bq, q);
  // C1: offset depthwise conv
  hipLaunchKernelGGL(k_offset_conv, dim3(32, 32), dim3(128), 0, stream,
                     q, off_dw_w, convo);
  // C2: offset post (LN + GELU + pointwise + tanh) -> pos
  hipLaunchKernelGGL(k_offset_post, dim3(16, 32), dim3(256), 0, stream,
                     convo, off_dw_b, off_ln_g, off_ln_b, off_pw_w,
                     posw, out_pos, out_ref);
  // D: bilinear sampling
  hipLaunchKernelGGL(k_sample, dim3(16, 32), dim3(256), 0, stream,
                     feat, posw, xs);
  // E: k, v projections
  hipLaunchKernelGGL(k_kv, dim3(64, 8), dim3(256), 0, stream,
                     xs, wkT, bk, wvT, bv, kk, vv);
  // F: attention (writes attn_out, aliases feat region)
  hipLaunchKernelGGL(k_attn, dim3(13, 64), dim3(256), 0, stream,
                     q, kk, vv, posw, rpe_w1, rpe_b1, rpe_w2, attn_out);
  // G: y = wo @ attn_out + bo
  hipLaunchKernelGGL(k_gemm256, dim3(1568), dim3(256), 0, stream,
                     attn_out, woT, bo, y);
}

// Round 4
// 303.664 us; speedup vs baseline: 3.2914x; 1.5269x over previous
//
#include <hip/hip_runtime.h>
#include <cstddef>

// Problem constants
// B=8, DIM=256, NH=8, H=W=56, G=4, CG=64, GH=2, HC=32, Hk=Wk=8, ns=64

typedef short bf16x8 __attribute__((ext_vector_type(8)));
typedef float f32x4 __attribute__((ext_vector_type(4)));

static __device__ __forceinline__ ushort f2bf(float f) {
  union { float f; unsigned u; } v; v.f = f;
  unsigned r = v.u + 0x7fffu + ((v.u >> 16) & 1u);   // RNE
  return (ushort)(r >> 16);
}
static __device__ __forceinline__ float bf2f(ushort u) {
  union { unsigned u; float f; } v; v.u = ((unsigned)u) << 16;
  return v.f;
}

// ws float offsets
#define OFF_FEATB 0u          // feat bf16 [b*3136+m][256c]: 6422528 bf16 = 3211264 fl
                              // (region reused later for attn-out bf16 pack)
#define OFF_Q     3211264u    // q fp32 [b][c][m]: 6422528 fl
#define OFF_POS   9633792u    // 4096
#define OFF_XS    9637888u    // 131072 (also offset-conv scratch earlier)
#define OFF_K     9768960u    // 131072
#define OFF_V     9900032u    // 131072
#define OFF_PWP   10031104u   // pw pack 49152 bf16 = 24576 fl
#define OFF_WQP   10055680u   // 65536 bf16 = 32768 fl
#define OFF_WOP   10088448u   // 32768 fl
#define OFF_WKT   10121216u   // 65536 fl
#define OFF_WVT   10186752u   // 65536 fl -> end 10252288 fl (41 MB)

// ---------------------------------------------------------------------------
// Kernel P: pack weights.
// y=0: patch_w [256][192] -> bf16 frag pack [k8][o][8]
// y=1: wq -> pack; y=2: wo -> pack; y=3: wkT fp32; y=4: wvT fp32
__global__ __launch_bounds__(256) void k_pack(
    const float* __restrict__ pw, const float* __restrict__ wq,
    const float* __restrict__ wk, const float* __restrict__ wv,
    const float* __restrict__ wo, ushort* __restrict__ pwp,
    ushort* __restrict__ wqp, ushort* __restrict__ wop,
    float* __restrict__ wkT, float* __restrict__ wvT) {
  const int o = blockIdx.x, t = threadIdx.x, m = blockIdx.y;
  if (m == 0) {
    if (t < 192) pwp[((t >> 3) * 256 + o) * 8 + (t & 7)] = f2bf(pw[o * 192 + t]);
  } else if (m == 1) {
    wqp[((t >> 3) * 256 + o) * 8 + (t & 7)] = f2bf(wq[o * 256 + t]);
  } else if (m == 2) {
    wop[((t >> 3) * 256 + o) * 8 + (t & 7)] = f2bf(wo[o * 256 + t]);
  } else if (m == 3) {
    wkT[t * 256 + o] = wk[o * 256 + t];
  } else {
    wvT[t * 256 + o] = wv[o * 256 + t];
  }
}

// ---------------------------------------------------------------------------
// Kernel A: patch conv (im2col MFMA, K=192) + bias + channel-LN.
// Block = 4 waves; wave = 16 queries x 256 channels (16 col-frags, acc 64 f32).
// A-frag: lane l holds x-window elems [row=l&15][k=(l>>4)*8+j] -> 2 float4 loads.
// Output: feat bf16 [m][c]  (this IS the A-pack for the q GEMM).
__global__ __launch_bounds__(256) void k_patch_mfma(
    const float* __restrict__ x, const ushort* __restrict__ pwp,
    const float* __restrict__ pb, const float* __restrict__ g1,
    const float* __restrict__ b1, ushort* __restrict__ featb) {
  const int t = threadIdx.x;
  const int lane = t & 63;
  const int wid = t >> 6;
  const int m_base = blockIdx.x * 64 + wid * 16;
  const int kg = lane >> 4;      // k-group 0..3
  const int lr = lane & 15;      // A-row / C-col sublane
  const int mA = m_base + lr;    // A-side query index
  const int bA = mA / 3136;
  const int posA = mA - bA * 3136;
  const int ohA = posA / 56;
  const int owA = posA - ohA * 56;

  f32x4 acc[16];
#pragma unroll
  for (int f = 0; f < 16; f++) {
    float bv = pb[f * 16 + lr];
    acc[f] = (f32x4){bv, bv, bv, bv};
  }
#pragma unroll
  for (int ks = 0; ks < 6; ks++) {
    const int k8 = ks * 4 + kg;
    const int ci = k8 >> 3, ii = k8 & 7;
    const float* xp =
        x + (((size_t)bA * 3 + ci) * 448 + (ohA * 8 + ii)) * 448 + owA * 8;
    float4 v0 = *(const float4*)xp;
    float4 v1 = *(const float4*)(xp + 4);
    bf16x8 a;
    a[0] = (short)f2bf(v0.x); a[1] = (short)f2bf(v0.y);
    a[2] = (short)f2bf(v0.z); a[3] = (short)f2bf(v0.w);
    a[4] = (short)f2bf(v1.x); a[5] = (short)f2bf(v1.y);
    a[6] = (short)f2bf(v1.z); a[7] = (short)f2bf(v1.w);
#pragma unroll
    for (int f = 0; f < 16; f++) {
      bf16x8 bfr = *(const bf16x8*)(pwp + (size_t)(k8 * 256 + f * 16 + lr) * 8);
      acc[f] = __builtin_amdgcn_mfma_f32_16x16x32_bf16(a, bfr, acc[f], 0, 0, 0);
    }
  }
  // LN per C-row (over all 256 cols, reduce across 16 lr-lanes)
  float mean[4], rstd[4];
#pragma unroll
  for (int j = 0; j < 4; j++) {
    float s1 = 0.f, s2 = 0.f;
#pragma unroll
    for (int f = 0; f < 16; f++) { float v = acc[f][j]; s1 += v; s2 += v * v; }
#pragma unroll
    for (int off = 8; off >= 1; off >>= 1) {
      s1 += __shfl_xor(s1, off);
      s2 += __shfl_xor(s2, off);
    }
    float mn = s1 * (1.f / 256.f);
    float var = s2 * (1.f / 256.f) - mn * mn;
    mean[j] = mn; rstd[j] = rsqrtf(var + 1e-5f);
  }
#pragma unroll
  for (int f = 0; f < 16; f++) {
    const int c = f * 16 + lr;
    const float gg = g1[c], bb = b1[c];
#pragma unroll
    for (int j = 0; j < 4; j++) {
      const int mo = m_base + kg * 4 + j;   // C-row
      float v = (acc[f][j] - mean[j]) * rstd[j] * gg + bb;
      featb[(size_t)mo * 256 + c] = f2bf(v);
    }
  }
}

// ---------------------------------------------------------------------------
// Kernel B: MFMA GEMM: out[b][o][m] = sum_c apk[m][c]*w[o][c] + bias[o].
// A bf16 [m][c] direct-global frags; B packed bf16; no main-loop LDS.
// 8 waves: 4 m-tiles x 2 n-halves. Epilogue: LDS transpose -> [c][m] coalesced.
__global__ __launch_bounds__(512) void k_gemm_mfma(
    const ushort* __restrict__ apk, const ushort* __restrict__ wp,
    const float* __restrict__ bias, float* __restrict__ out) {
  const int t = threadIdx.x;
  const int lane = t & 63;
  const int wid = t >> 6;             // 0..7
  const int mt = wid >> 1, nh = wid & 1;
  const int lr = lane & 15, kg = lane >> 4;
  const int m_base = blockIdx.x * 64 + mt * 16;
  const int mA = m_base + lr;

  f32x4 acc[8];
#pragma unroll
  for (int f = 0; f < 8; f++) {
    float bv = bias[nh * 128 + f * 16 + lr];
    acc[f] = (f32x4){bv, bv, bv, bv};
  }
  const ushort* arow = apk + (size_t)mA * 256;
#pragma unroll
  for (int ks = 0; ks < 8; ks++) {
    bf16x8 a = *(const bf16x8*)(arow + ks * 32 + kg * 8);
#pragma unroll
    for (int f = 0; f < 8; f++) {
      const int o = nh * 128 + f * 16 + lr;
      bf16x8 bfr = *(const bf16x8*)(wp + (size_t)((ks * 4 + kg) * 256 + o) * 8);
      acc[f] = __builtin_amdgcn_mfma_f32_16x16x32_bf16(a, bfr, acc[f], 0, 0, 0);
    }
  }
  __shared__ float sA[64 * 257];
#pragma unroll
  for (int f = 0; f < 8; f++) {
#pragma unroll
    for (int j = 0; j < 4; j++)
      sA[(mt * 16 + kg * 4 + j) * 257 + nh * 128 + f * 16 + lr] = acc[f][j];
  }
  __syncthreads();
  const int b = (blockIdx.x * 64) / 3136;
  const int pos0 = (blockIdx.x * 64) % 3136;
#pragma unroll
  for (int i = 0; i < 32; i++) {
    int idx = t + i * 512;
    int c = idx >> 6, mm = idx & 63;
    out[((size_t)b * 256 + c) * 3136 + pos0 + mm] = sA[mm * 257 + c];
  }
}

// ---------------------------------------------------------------------------
// Kernel C1: offset depthwise conv (28x28, stride 8, pad 14), one wave per
// (bg, channel). Channel plane staged in LDS with zero halo + bank swizzle.
__global__ __launch_bounds__(128) void k_offset_conv(
    const float* __restrict__ q, const float* __restrict__ dww,
    float* __restrict__ convo) {
  const int bg = blockIdx.y;               // 0..31
  const int wv = threadIdx.x >> 6;         // 0..1
  const int lane = threadIdx.x & 63;
  const int ch = blockIdx.x * 2 + wv;      // 0..63
  const int b = bg >> 2, g = bg & 3;

  __shared__ float pl[2][7072];
  float* P = pl[wv];
  for (int idx = lane; idx < 7072; idx += 64) P[idx] = 0.f;

  const float* qb = q + ((size_t)b * 256 + g * 64 + ch) * 3136;
  if (lane < 56) {
    for (int r = 0; r < 56; r++) {
      int hr = r + 14;
      P[hr * 84 + (lane + 14) + (hr >> 3)] = qb[r * 56 + lane];
    }
  }
  // same-wave DS ops are program-ordered; compute reads only this wave's plane

  const int oh = lane >> 3, ow = lane & 7;
  const int chs = __builtin_amdgcn_readfirstlane(ch);
  const float* wr = dww + (size_t)chs * 784;
  float acc = 0.f;
  const int r0 = oh * 8, c0 = ow * 8;
  for (int i = 0; i < 28; i++) {
    int hr = r0 + i;
    const float* prow = P + hr * 84 + c0 + (hr >> 3);
    const float* wrr = wr + i * 28;
#pragma unroll
    for (int j = 0; j < 28; j++)
      acc = fmaf(prow[j], wrr[j], acc);
  }
  convo[bg * 4096 + lane * 64 + ch] = acc;
}

// ---------------------------------------------------------------------------
// Kernel C2: LN(64) + GELU + pointwise(2x64) + tanh + reference points.
__global__ __launch_bounds__(256) void k_offset_post(
    const float* __restrict__ convo, const float* __restrict__ dwb,
    const float* __restrict__ lng, const float* __restrict__ lnb,
    const float* __restrict__ pww, float* __restrict__ pos_ws,
    float* __restrict__ out_pos, float* __restrict__ out_ref) {
  const int bg = blockIdx.y;               // 0..31
  const int wv = threadIdx.x >> 6;         // 0..3
  const int lane = threadIdx.x & 63;       // cg
  const int idx = blockIdx.x * 4 + wv;     // 0..63
  const int oh = idx >> 3, ow = idx & 7;

  float acc = convo[bg * 4096 + idx * 64 + lane] + dwb[lane];

  float s1 = acc, s2 = acc * acc;
#pragma unroll
  for (int off = 32; off >= 1; off >>= 1) {
    s1 += __shfl_xor(s1, off);
    s2 += __shfl_xor(s2, off);
  }
  float m = s1 * (1.f / 64.f);
  float var = s2 * (1.f / 64.f) - m * m;
  float val = (acc - m) * rsqrtf(var + 1e-5f) * lng[lane] + lnb[lane];
  val = 0.5f * val * (1.f + erff(val * 0.70710678118654752f));
  float p0 = pww[lane] * val, p1 = pww[64 + lane] * val;
#pragma unroll
  for (int off = 32; off >= 1; off >>= 1) {
    p0 += __shfl_xor(p0, off);
    p1 += __shfl_xor(p1, off);
  }
  if (lane == 0) {
    float offy = tanhf(p0) * (2.0f / 7.0f);
    float offx = tanhf(p1) * (2.0f / 7.0f);
    float ry = (0.5f + oh) * (2.0f / 7.0f) - 1.0f;
    float rx = (0.5f + ow) * (2.0f / 7.0f) - 1.0f;
    float py = offy + ry, px = offx + rx;
    int o = bg * 128 + idx * 2;
    pos_ws[o] = py;  pos_ws[o + 1] = px;
    out_pos[o] = py; out_pos[o + 1] = px;
    out_ref[o] = ry; out_ref[o + 1] = rx;
  }
}

// ---------------------------------------------------------------------------
// Kernel D: bilinear sampling from bf16 feat [m][c]: corner gathers are
// 64-lane contiguous (128B) now. One wave per sample point.
__global__ __launch_bounds__(256) void k_sample(
    const ushort* __restrict__ featb, const float* __restrict__ pos_ws,
    float* __restrict__ xs) {
  const int bg = blockIdx.y;
  const int wv = threadIdx.x >> 6, lane = threadIdx.x & 63;
  const int n = blockIdx.x * 4 + wv;
  const int b = bg >> 2, g = bg & 3;

  float py = pos_ws[bg * 128 + n * 2];
  float px = pos_ws[bg * 128 + n * 2 + 1];
  float gx = (px + 1.f) * 0.5f * 55.f;
  float gy = (py + 1.f) * 0.5f * 55.f;
  float x0f = floorf(gx), y0f = floorf(gy);
  int x0 = (int)x0f, y0 = (int)y0f;
  float wx1 = gx - x0f, wx0 = 1.f - wx1;
  float wy1 = gy - y0f, wy0 = 1.f - wy1;

  const size_t mb = (size_t)b * 3136;
  const int cofs = g * 64 + lane;
  float acc = 0.f;
  if (x0 >= 0 && x0 <= 55 && y0 >= 0 && y0 <= 55)
    acc = fmaf(bf2f(featb[(mb + y0 * 56 + x0) * 256 + cofs]), wx0 * wy0, acc);
  if (x0 + 1 >= 0 && x0 + 1 <= 55 && y0 >= 0 && y0 <= 55)
    acc = fmaf(bf2f(featb[(mb + y0 * 56 + x0 + 1) * 256 + cofs]), wx1 * wy0, acc);
  if (x0 >= 0 && x0 <= 55 && y0 + 1 >= 0 && y0 + 1 <= 55)
    acc = fmaf(bf2f(featb[(mb + (y0 + 1) * 56 + x0) * 256 + cofs]), wx0 * wy1, acc);
  if (x0 + 1 >= 0 && x0 + 1 <= 55 && y0 + 1 >= 0 && y0 + 1 <= 55)
    acc = fmaf(bf2f(featb[(mb + (y0 + 1) * 56 + x0 + 1) * 256 + cofs]), wx1 * wy1, acc);

  xs[((size_t)bg * 64 + lane) * 64 + n] = acc;
}

// ---------------------------------------------------------------------------
// Kernel E: k,v projections on sampled features. One block per (b, n).
__global__ __launch_bounds__(256) void k_kv(
    const float* __restrict__ xs, const float* __restrict__ wkT,
    const float* __restrict__ bk, const float* __restrict__ wvT,
    const float* __restrict__ bv, float* __restrict__ ko,
    float* __restrict__ vo) {
  const int b = blockIdx.y;   // 0..7
  const int n = blockIdx.x;   // 0..63
  const int t = threadIdx.x;
  __shared__ float sxs[256];
  sxs[t] = xs[((size_t)b * 256 + t) * 64 + n];
  __syncthreads();
  float ak = bk[t], av = bv[t];
  for (int c = 0; c < 256; c++) {
    float xv = sxs[c];
    ak = fmaf(wkT[c * 256 + t], xv, ak);
    av = fmaf(wvT[c * 256 + t], xv, av);
  }
  ko[((size_t)b * 256 + t) * 64 + n] = ak;
  vo[((size_t)b * 256 + t) * 64 + n] = av;
}

// ---------------------------------------------------------------------------
// Kernel F: attention. One thread per query; K/V/pos/rpe staged in LDS.
// Output: bf16 pack [m][c] (the A-side for the o-projection GEMM).
__global__ __launch_bounds__(256) void k_attn(
    const float* __restrict__ qws, const float* __restrict__ kws,
    const float* __restrict__ vws, const float* __restrict__ pos_ws,
    const float* __restrict__ w1, const float* __restrict__ b1,
    const float* __restrict__ w2, ushort* __restrict__ attnpk) {
  const int bh = blockIdx.y;          // 0..63
  const int b = bh >> 3, h = bh & 7;
  const int g = h >> 1, gh = h & 1;
  const int bg = b * 4 + g;
  const int t = threadIdx.x;

  __shared__ float Kt[64][36];        // [n][cc], padded
  __shared__ float Vt[64][36];
  __shared__ float posl[128];
  __shared__ float rpe4[32][4];       // {w1y, w1x, b1, w2[gh]}

  const float* kp = kws + ((size_t)b * 256 + h * 32) * 64;
  const float* vp = vws + ((size_t)b * 256 + h * 32) * 64;
  for (int i = t; i < 2048; i += 256) {
    int cc = i >> 6, n = i & 63;
    Kt[n][cc] = kp[i];
    Vt[n][cc] = vp[i];
  }
  if (t < 128) posl[t] = pos_ws[bg * 128 + t];
  if (t < 32) {
    rpe4[t][0] = w1[t * 2];
    rpe4[t][1] = w1[t * 2 + 1];
    rpe4[t][2] = b1[t];
    rpe4[t][3] = w2[gh * 32 + t];
  }
  __syncthreads();

  const int m = blockIdx.x * 256 + t;
  if (m >= 3136) return;
  const int my = m / 56, mx = m % 56;
  const float qgy = ((float)my * (56.0f / 55.0f)) * (2.0f / 55.0f) - 1.0f;
  const float qgx = ((float)mx * (56.0f / 55.0f)) * (2.0f / 55.0f) - 1.0f;

  float qv[32];
  const float* qp = qws + ((size_t)b * 256 + h * 32) * 3136 + m;
#pragma unroll
  for (int cc = 0; cc < 32; cc++) qv[cc] = qp[cc * 3136];

  const float scale = 0.17677669529663687f;  // 1/sqrt(32)
  float p[64];
  float mmax = -1e30f;
#pragma unroll
  for (int n = 0; n < 64; n++) {
    float s = 0.f;
    const float4* kk = (const float4*)Kt[n];
#pragma unroll
    for (int c4 = 0; c4 < 8; c4++) {
      float4 kv = kk[c4];
      s = fmaf(qv[c4 * 4 + 0], kv.x, s);
      s = fmaf(qv[c4 * 4 + 1], kv.y, s);
      s = fmaf(qv[c4 * 4 + 2], kv.z, s);
      s = fmaf(qv[c4 * 4 + 3], kv.w, s);
    }
    s *= scale;
    float dy = (qgy - posl[n * 2]) * 4.f;
    float dx = (qgx - posl[n * 2 + 1]) * 4.f;
    float ty = copysignf(log2f(fabsf(dy) + 1.f) * (1.f / 3.f), dy);
    float tx = copysignf(log2f(fabsf(dx) + 1.f) * (1.f / 3.f), dx);
    float biasv = 0.f;
#pragma unroll
    for (int j = 0; j < 32; j++) {
      float4 r = *(const float4*)rpe4[j];
      float hv = fmaf(r.x, ty, fmaf(r.y, tx, r.z));
      hv = fmaxf(hv, 0.f);
      biasv = fmaf(r.w, hv, biasv);
    }
    s += biasv;
    p[n] = s;
    mmax = fmaxf(mmax, s);
  }
  float sum = 0.f;
#pragma unroll
  for (int n = 0; n < 64; n++) {
    float e = __expf(p[n] - mmax);
    p[n] = e;
    sum += e;
  }
  float inv = 1.f / sum;

  float acc[32];
#pragma unroll
  for (int cc = 0; cc < 32; cc++) acc[cc] = 0.f;
#pragma unroll
  for (int n = 0; n < 64; n++) {
    float pw_ = p[n];
    const float4* vv = (const float4*)Vt[n];
#pragma unroll
    for (int c4 = 0; c4 < 8; c4++) {
      float4 v4 = vv[c4];
      acc[c4 * 4 + 0] = fmaf(pw_, v4.x, acc[c4 * 4 + 0]);
      acc[c4 * 4 + 1] = fmaf(pw_, v4.y, acc[c4 * 4 + 1]);
      acc[c4 * 4 + 2] = fmaf(pw_, v4.z, acc[c4 * 4 + 2]);
      acc[c4 * 4 + 3] = fmaf(pw_, v4.w, acc[c4 * 4 + 3]);
    }
  }
  ushort* op = attnpk + ((size_t)(b * 3136 + m)) * 256 + h * 32;
#pragma unroll
  for (int c8 = 0; c8 < 4; c8++) {
    bf16x8 o8;
#pragma unroll
    for (int j = 0; j < 8; j++) o8[j] = (short)f2bf(acc[c8 * 8 + j] * inv);
    *(bf16x8*)(op + c8 * 8) = o8;
  }
}

// ---------------------------------------------------------------------------
extern "C" void kernel_launch(void* const* d_in, const int* in_sizes, int n_in,
                              void* d_out, int out_size, void* d_ws,
                              size_t ws_size, hipStream_t stream) {
  const float* x       = (const float*)d_in[0];
  const float* patch_w = (const float*)d_in[1];
  const float* patch_b = (const float*)d_in[2];
  const float* ln1_g   = (const float*)d_in[3];
  const float* ln1_b   = (const float*)d_in[4];
  const float* wq      = (const float*)d_in[5];
  const float* bq      = (const float*)d_in[6];
  const float* wk      = (const float*)d_in[7];
  const float* bk      = (const float*)d_in[8];
  const float* wv      = (const float*)d_in[9];
  const float* bv      = (const float*)d_in[10];
  const float* wo      = (const float*)d_in[11];
  const float* bo      = (const float*)d_in[12];
  const float* off_dw_w = (const float*)d_in[13];
  const float* off_dw_b = (const float*)d_in[14];
  const float* off_ln_g = (const float*)d_in[15];
  const float* off_ln_b = (const float*)d_in[16];
  const float* off_pw_w = (const float*)d_in[17];
  const float* rpe_w1  = (const float*)d_in[18];
  const float* rpe_b1  = (const float*)d_in[19];
  const float* rpe_w2  = (const float*)d_in[20];

  float* ws = (float*)d_ws;
  ushort* featb = (ushort*)(ws + OFF_FEATB);   // bf16 [m][c]
  ushort* attnpk = featb;                      // reuse (feat dead after sample)
  float* q    = ws + OFF_Q;
  float* posw = ws + OFF_POS;
  float* xs   = ws + OFF_XS;
  float* kk   = ws + OFF_K;
  float* vv   = ws + OFF_V;
  float* convo = ws + OFF_XS;                  // alias xs (dead before xs)
  ushort* pwp = (ushort*)(ws + OFF_PWP);
  ushort* wqp = (ushort*)(ws + OFF_WQP);
  ushort* wop = (ushort*)(ws + OFF_WOP);
  float* wkT  = ws + OFF_WKT;
  float* wvT  = ws + OFF_WVT;

  float* y = (float*)d_out;
  float* out_pos = y + 6422528;
  float* out_ref = out_pos + 4096;

  // P: weight packs / transposes
  hipLaunchKernelGGL(k_pack, dim3(256, 5), dim3(256), 0, stream,
                     patch_w, wq, wk, wv, wo, pwp, wqp, wop, wkT, wvT);
  // A: patch embed conv (MFMA) + LN -> feat bf16 [m][c]
  hipLaunchKernelGGL(k_patch_mfma, dim3(392), dim3(256), 0, stream,
                     x, pwp, patch_b, ln1_g, ln1_b, featb);
  // B: q = wq @ feat + bq   (out fp32 [c][m])
  hipLaunchKernelGGL(k_gemm_mfma, dim3(392), dim3(512), 0, stream,
                     featb, wqp, bq, q);
  // C1: offset depthwise conv
  hipLaunchKernelGGL(k_offset_conv, dim3(32, 32), dim3(128), 0, stream,
                     q, off_dw_w, convo);
  // C2: offset post (LN + GELU + pointwise + tanh) -> pos
  hipLaunchKernelGGL(k_offset_post, dim3(16, 32), dim3(256), 0, stream,
                     convo, off_dw_b, off_ln_g, off_ln_b, off_pw_w,
                     posw, out_pos, out_ref);
  // D: bilinear sampling (bf16 feat, coalesced)
  hipLaunchKernelGGL(k_sample, dim3(16, 32), dim3(256), 0, stream,
                     featb, posw, xs);
  // E: k, v projections
  hipLaunchKernelGGL(k_kv, dim3(64, 8), dim3(256), 0, stream,
                     xs, wkT, bk, wvT, bv, kk, vv);
  // F: attention -> bf16 pack [m][c] (overwrites feat region; feat is dead)
  hipLaunchKernelGGL(k_attn, dim3(13, 64), dim3(256), 0, stream,
                     q, kk, vv, posw, rpe_w1, rpe_b1, rpe_w2, attnpk);
  // G: y = wo @ attn_out + bo  (out fp32 [c][m] = d_out)
  hipLaunchKernelGGL(k_gemm_mfma, dim3(392), dim3(512), 0, stream,
                     attnpk, wop, bo, y);
}

// Round 5
// 239.974 us; speedup vs baseline: 4.1649x; 1.2654x over previous
//
#include <hip/hip_runtime.h>
#include <cstddef>

// Problem constants
// B=8, DIM=256, NH=8, H=W=56, G=4, CG=64, GH=2, HC=32, Hk=Wk=8, ns=64

typedef short bf16x8 __attribute__((ext_vector_type(8)));
typedef float f32x4 __attribute__((ext_vector_type(4)));

static __device__ __forceinline__ ushort f2bf(float f) {
  union { float f; unsigned u; } v; v.f = f;
  unsigned r = v.u + 0x7fffu + ((v.u >> 16) & 1u);   // RNE
  return (ushort)(r >> 16);
}
static __device__ __forceinline__ float bf2f(ushort u) {
  union { unsigned u; float f; } v; v.u = ((unsigned)u) << 16;
  return v.f;
}

// ws float offsets
#define OFF_FEATB 0u          // feat bf16 [b*3136+m][256c] (later reused as attnpk)
#define OFF_QPK   3211264u    // q bf16 [b*3136+m][256c]
#define OFF_Q     6422528u    // q fp32 [b][c][m]
#define OFF_POS   12845056u   // 4096
#define OFF_XS    12849152u   // 131072 (also offset-conv scratch earlier)
#define OFF_KPK   12980224u   // K bf16 pack [b][h][c8=4][n=64][8]: 131072 bf16
#define OFF_VPK   13045760u   // V bf16 pack [b][h][n8=8][c=32][8]: 131072 bf16
#define OFF_PWP   13111296u   // pw pack 49152 bf16
#define OFF_WQP   13135872u   // 65536 bf16
#define OFF_WOP   13168640u   // 65536 bf16
#define OFF_WKT   13201408u   // 65536 fl
#define OFF_WVT   13266944u   // 65536 fl -> end 13332480 fl (53.3 MB)

// ---------------------------------------------------------------------------
// Kernel P: pack weights.
__global__ __launch_bounds__(256) void k_pack(
    const float* __restrict__ pw, const float* __restrict__ wq,
    const float* __restrict__ wk, const float* __restrict__ wv,
    const float* __restrict__ wo, ushort* __restrict__ pwp,
    ushort* __restrict__ wqp, ushort* __restrict__ wop,
    float* __restrict__ wkT, float* __restrict__ wvT) {
  const int o = blockIdx.x, t = threadIdx.x, m = blockIdx.y;
  if (m == 0) {
    if (t < 192) pwp[((t >> 3) * 256 + o) * 8 + (t & 7)] = f2bf(pw[o * 192 + t]);
  } else if (m == 1) {
    wqp[((t >> 3) * 256 + o) * 8 + (t & 7)] = f2bf(wq[o * 256 + t]);
  } else if (m == 2) {
    wop[((t >> 3) * 256 + o) * 8 + (t & 7)] = f2bf(wo[o * 256 + t]);
  } else if (m == 3) {
    wkT[t * 256 + o] = wk[o * 256 + t];
  } else {
    wvT[t * 256 + o] = wv[o * 256 + t];
  }
}

// ---------------------------------------------------------------------------
// Kernel A: patch conv (im2col MFMA, K=192) + bias + channel-LN -> bf16 [m][c]
__global__ __launch_bounds__(256) void k_patch_mfma(
    const float* __restrict__ x, const ushort* __restrict__ pwp,
    const float* __restrict__ pb, const float* __restrict__ g1,
    const float* __restrict__ b1, ushort* __restrict__ featb) {
  const int t = threadIdx.x;
  const int lane = t & 63;
  const int wid = t >> 6;
  const int m_base = blockIdx.x * 64 + wid * 16;
  const int kg = lane >> 4;
  const int lr = lane & 15;
  const int mA = m_base + lr;
  const int bA = mA / 3136;
  const int posA = mA - bA * 3136;
  const int ohA = posA / 56;
  const int owA = posA - ohA * 56;

  f32x4 acc[16];
#pragma unroll
  for (int f = 0; f < 16; f++) {
    float bv = pb[f * 16 + lr];
    acc[f] = (f32x4){bv, bv, bv, bv};
  }
#pragma unroll
  for (int ks = 0; ks < 6; ks++) {
    const int k8 = ks * 4 + kg;
    const int ci = k8 >> 3, ii = k8 & 7;
    const float* xp =
        x + (((size_t)bA * 3 + ci) * 448 + (ohA * 8 + ii)) * 448 + owA * 8;
    float4 v0 = *(const float4*)xp;
    float4 v1 = *(const float4*)(xp + 4);
    bf16x8 a;
    a[0] = (short)f2bf(v0.x); a[1] = (short)f2bf(v0.y);
    a[2] = (short)f2bf(v0.z); a[3] = (short)f2bf(v0.w);
    a[4] = (short)f2bf(v1.x); a[5] = (short)f2bf(v1.y);
    a[6] = (short)f2bf(v1.z); a[7] = (short)f2bf(v1.w);
#pragma unroll
    for (int f = 0; f < 16; f++) {
      bf16x8 bfr = *(const bf16x8*)(pwp + (size_t)(k8 * 256 + f * 16 + lr) * 8);
      acc[f] = __builtin_amdgcn_mfma_f32_16x16x32_bf16(a, bfr, acc[f], 0, 0, 0);
    }
  }
  float mean[4], rstd[4];
#pragma unroll
  for (int j = 0; j < 4; j++) {
    float s1 = 0.f, s2 = 0.f;
#pragma unroll
    for (int f = 0; f < 16; f++) { float v = acc[f][j]; s1 += v; s2 += v * v; }
#pragma unroll
    for (int off = 8; off >= 1; off >>= 1) {
      s1 += __shfl_xor(s1, off);
      s2 += __shfl_xor(s2, off);
    }
    float mn = s1 * (1.f / 256.f);
    float var = s2 * (1.f / 256.f) - mn * mn;
    mean[j] = mn; rstd[j] = rsqrtf(var + 1e-5f);
  }
#pragma unroll
  for (int f = 0; f < 16; f++) {
    const int c = f * 16 + lr;
    const float gg = g1[c], bb = b1[c];
#pragma unroll
    for (int j = 0; j < 4; j++) {
      const int mo = m_base + kg * 4 + j;
      float v = (acc[f][j] - mean[j]) * rstd[j] * gg + bb;
      featb[(size_t)mo * 256 + c] = f2bf(v);
    }
  }
}

// ---------------------------------------------------------------------------
// Kernel B: MFMA GEMM: out fp32 [b][o][m]; optional bf16 [m][o] pack (opk).
__global__ __launch_bounds__(512) void k_gemm_mfma(
    const ushort* __restrict__ apk, const ushort* __restrict__ wp,
    const float* __restrict__ bias, float* __restrict__ out,
    ushort* __restrict__ opk) {
  const int t = threadIdx.x;
  const int lane = t & 63;
  const int wid = t >> 6;
  const int mt = wid >> 1, nh = wid & 1;
  const int lr = lane & 15, kg = lane >> 4;
  const int m_base = blockIdx.x * 64 + mt * 16;
  const int mA = m_base + lr;

  f32x4 acc[8];
#pragma unroll
  for (int f = 0; f < 8; f++) {
    float bv = bias[nh * 128 + f * 16 + lr];
    acc[f] = (f32x4){bv, bv, bv, bv};
  }
  const ushort* arow = apk + (size_t)mA * 256;
#pragma unroll
  for (int ks = 0; ks < 8; ks++) {
    bf16x8 a = *(const bf16x8*)(arow + ks * 32 + kg * 8);
#pragma unroll
    for (int f = 0; f < 8; f++) {
      const int o = nh * 128 + f * 16 + lr;
      bf16x8 bfr = *(const bf16x8*)(wp + (size_t)((ks * 4 + kg) * 256 + o) * 8);
      acc[f] = __builtin_amdgcn_mfma_f32_16x16x32_bf16(a, bfr, acc[f], 0, 0, 0);
    }
  }
  __shared__ float sA[64 * 257];
#pragma unroll
  for (int f = 0; f < 8; f++) {
#pragma unroll
    for (int j = 0; j < 4; j++)
      sA[(mt * 16 + kg * 4 + j) * 257 + nh * 128 + f * 16 + lr] = acc[f][j];
  }
  __syncthreads();
  const int b = (blockIdx.x * 64) / 3136;
  const int pos0 = (blockIdx.x * 64) % 3136;
#pragma unroll
  for (int i = 0; i < 32; i++) {
    int idx = t + i * 512;
    int c = idx >> 6, mm = idx & 63;
    out[((size_t)b * 256 + c) * 3136 + pos0 + mm] = sA[mm * 257 + c];
  }
  if (opk) {
    const int mm = t & 63;
    const int cs = t >> 6;   // 0..7
#pragma unroll
    for (int i = 0; i < 4; i++) {
      int c0 = cs * 32 + i * 8;
      bf16x8 v8;
#pragma unroll
      for (int j = 0; j < 8; j++) v8[j] = (short)f2bf(sA[mm * 257 + c0 + j]);
      *(bf16x8*)(opk + ((size_t)(blockIdx.x * 64 + mm)) * 256 + c0) = v8;
    }
  }
}

// ---------------------------------------------------------------------------
// Kernel C1: offset depthwise conv (28x28, stride 8, pad 14).
__global__ __launch_bounds__(128) void k_offset_conv(
    const float* __restrict__ q, const float* __restrict__ dww,
    float* __restrict__ convo) {
  const int bg = blockIdx.y;
  const int wv = threadIdx.x >> 6;
  const int lane = threadIdx.x & 63;
  const int ch = blockIdx.x * 2 + wv;
  const int b = bg >> 2, g = bg & 3;

  __shared__ float pl[2][7072];
  float* P = pl[wv];
  for (int idx = lane; idx < 7072; idx += 64) P[idx] = 0.f;

  const float* qb = q + ((size_t)b * 256 + g * 64 + ch) * 3136;
  if (lane < 56) {
    for (int r = 0; r < 56; r++) {
      int hr = r + 14;
      P[hr * 84 + (lane + 14) + (hr >> 3)] = qb[r * 56 + lane];
    }
  }
  const int oh = lane >> 3, ow = lane & 7;
  const int chs = __builtin_amdgcn_readfirstlane(ch);
  const float* wr = dww + (size_t)chs * 784;
  float acc = 0.f;
  const int r0 = oh * 8, c0 = ow * 8;
  for (int i = 0; i < 28; i++) {
    int hr = r0 + i;
    const float* prow = P + hr * 84 + c0 + (hr >> 3);
    const float* wrr = wr + i * 28;
#pragma unroll
    for (int j = 0; j < 28; j++)
      acc = fmaf(prow[j], wrr[j], acc);
  }
  convo[bg * 4096 + lane * 64 + ch] = acc;
}

// ---------------------------------------------------------------------------
// Kernel C2: LN(64) + GELU + pointwise(2x64) + tanh + reference points.
__global__ __launch_bounds__(256) void k_offset_post(
    const float* __restrict__ convo, const float* __restrict__ dwb,
    const float* __restrict__ lng, const float* __restrict__ lnb,
    const float* __restrict__ pww, float* __restrict__ pos_ws,
    float* __restrict__ out_pos, float* __restrict__ out_ref) {
  const int bg = blockIdx.y;
  const int wv = threadIdx.x >> 6;
  const int lane = threadIdx.x & 63;
  const int idx = blockIdx.x * 4 + wv;
  const int oh = idx >> 3, ow = idx & 7;

  float acc = convo[bg * 4096 + idx * 64 + lane] + dwb[lane];

  float s1 = acc, s2 = acc * acc;
#pragma unroll
  for (int off = 32; off >= 1; off >>= 1) {
    s1 += __shfl_xor(s1, off);
    s2 += __shfl_xor(s2, off);
  }
  float m = s1 * (1.f / 64.f);
  float var = s2 * (1.f / 64.f) - m * m;
  float val = (acc - m) * rsqrtf(var + 1e-5f) * lng[lane] + lnb[lane];
  val = 0.5f * val * (1.f + erff(val * 0.70710678118654752f));
  float p0 = pww[lane] * val, p1 = pww[64 + lane] * val;
#pragma unroll
  for (int off = 32; off >= 1; off >>= 1) {
    p0 += __shfl_xor(p0, off);
    p1 += __shfl_xor(p1, off);
  }
  if (lane == 0) {
    float offy = tanhf(p0) * (2.0f / 7.0f);
    float offx = tanhf(p1) * (2.0f / 7.0f);
    float ry = (0.5f + oh) * (2.0f / 7.0f) - 1.0f;
    float rx = (0.5f + ow) * (2.0f / 7.0f) - 1.0f;
    float py = offy + ry, px = offx + rx;
    int o = bg * 128 + idx * 2;
    pos_ws[o] = py;  pos_ws[o + 1] = px;
    out_pos[o] = py; out_pos[o + 1] = px;
    out_ref[o] = ry; out_ref[o + 1] = rx;
  }
}

// ---------------------------------------------------------------------------
// Kernel D: bilinear sampling from bf16 feat [m][c].
__global__ __launch_bounds__(256) void k_sample(
    const ushort* __restrict__ featb, const float* __restrict__ pos_ws,
    float* __restrict__ xs) {
  const int bg = blockIdx.y;
  const int wv = threadIdx.x >> 6, lane = threadIdx.x & 63;
  const int n = blockIdx.x * 4 + wv;
  const int b = bg >> 2, g = bg & 3;

  float py = pos_ws[bg * 128 + n * 2];
  float px = pos_ws[bg * 128 + n * 2 + 1];
  float gx = (px + 1.f) * 0.5f * 55.f;
  float gy = (py + 1.f) * 0.5f * 55.f;
  float x0f = floorf(gx), y0f = floorf(gy);
  int x0 = (int)x0f, y0 = (int)y0f;
  float wx1 = gx - x0f, wx0 = 1.f - wx1;
  float wy1 = gy - y0f, wy0 = 1.f - wy1;

  const size_t mb = (size_t)b * 3136;
  const int cofs = g * 64 + lane;
  float acc = 0.f;
  if (x0 >= 0 && x0 <= 55 && y0 >= 0 && y0 <= 55)
    acc = fmaf(bf2f(featb[(mb + y0 * 56 + x0) * 256 + cofs]), wx0 * wy0, acc);
  if (x0 + 1 >= 0 && x0 + 1 <= 55 && y0 >= 0 && y0 <= 55)
    acc = fmaf(bf2f(featb[(mb + y0 * 56 + x0 + 1) * 256 + cofs]), wx1 * wy0, acc);
  if (x0 >= 0 && x0 <= 55 && y0 + 1 >= 0 && y0 + 1 <= 55)
    acc = fmaf(bf2f(featb[(mb + (y0 + 1) * 56 + x0) * 256 + cofs]), wx0 * wy1, acc);
  if (x0 + 1 >= 0 && x0 + 1 <= 55 && y0 + 1 >= 0 && y0 + 1 <= 55)
    acc = fmaf(bf2f(featb[(mb + (y0 + 1) * 56 + x0 + 1) * 256 + cofs]), wx1 * wy1, acc);

  xs[((size_t)bg * 64 + lane) * 64 + n] = acc;
}

// ---------------------------------------------------------------------------
// Kernel E: k,v projections -> bf16 MFMA B-frag packs.
// kpk [b][h][c8=4][n=64][8] ; vpk [b][h][n8=8][c=32][8]
__global__ __launch_bounds__(256) void k_kv(
    const float* __restrict__ xs, const float* __restrict__ wkT,
    const float* __restrict__ bk, const float* __restrict__ wvT,
    const float* __restrict__ bv, ushort* __restrict__ kpk,
    ushort* __restrict__ vpk) {
  const int b = blockIdx.y;   // 0..7
  const int n = blockIdx.x;   // 0..63
  const int t = threadIdx.x;
  __shared__ float sxs[256];
  sxs[t] = xs[((size_t)b * 256 + t) * 64 + n];
  __syncthreads();
  float ak = bk[t], av = bv[t];
  for (int c = 0; c < 256; c++) {
    float xv = sxs[c];
    ak = fmaf(wkT[c * 256 + t], xv, ak);
    av = fmaf(wvT[c * 256 + t], xv, av);
  }
  const int h = t >> 5, cc = t & 31;
  const size_t base = (size_t)(b * 8 + h) * 2048;
  kpk[base + (size_t)((cc >> 3) * 64 + n) * 8 + (cc & 7)] = f2bf(ak);
  vpk[base + (size_t)((n >> 3) * 32 + cc) * 8 + (n & 7)] = f2bf(av);
}

// ---------------------------------------------------------------------------
// Kernel F: MFMA attention. Block = (b, g, 64-query tile); 4 waves x 16 q.
// Bias MLP computed once per (m,n) for both heads (wave-private LDS rows).
__global__ __launch_bounds__(256) void k_attn_mfma(
    const ushort* __restrict__ qpk, const ushort* __restrict__ kpk,
    const ushort* __restrict__ vpk, const float* __restrict__ pos_ws,
    const float* __restrict__ w1, const float* __restrict__ b1,
    const float* __restrict__ w2, ushort* __restrict__ attnpk) {
  const int bg = blockIdx.y;           // b*4+g
  const int b = bg >> 2, g = bg & 3;
  const int m0 = blockIdx.x * 64;
  const int t = threadIdx.x;
  const int lane = t & 63, w = t >> 6;

  __shared__ float bias0[64 * 68];     // row stride 68 f32 (=272B); reused as out tile
  __shared__ float bias1[64 * 68];
  __shared__ ushort Pbuf[4][16 * 72];  // per-wave P staging
  __shared__ float posl[128];
  __shared__ float4 rpe4[32];          // {w1y, w1x, b1, w2[0]}
  __shared__ float rpeB[32];           // w2[1]

  if (t < 128) posl[t] = pos_ws[bg * 128 + t];
  if (t < 32) {
    rpe4[t] = make_float4(w1[t * 2], w1[t * 2 + 1], b1[t], w2[t]);
    rpeB[t] = w2[32 + t];
  }
  __syncthreads();

  // Phase 1: bias tiles. Thread t covers row i=t>>2 (wave-private), n0..n0+15.
  {
    const int i = t >> 2;
    const int n0 = (t & 3) * 16;
    const int m = m0 + i;
    const int my = m / 56, mx = m % 56;
    const float qgy = (float)my * (56.0f / 55.0f) * (2.0f / 55.0f) - 1.0f;
    const float qgx = (float)mx * (56.0f / 55.0f) * (2.0f / 55.0f) - 1.0f;
    float ty[16], tx[16], a0[16], a1[16];
#pragma unroll
    for (int u = 0; u < 16; u++) {
      int n = n0 + u;
      float dy = (qgy - posl[2 * n]) * 4.f;
      float dx = (qgx - posl[2 * n + 1]) * 4.f;
      ty[u] = copysignf(log2f(fabsf(dy) + 1.f) * (1.f / 3.f), dy);
      tx[u] = copysignf(log2f(fabsf(dx) + 1.f) * (1.f / 3.f), dx);
      a0[u] = 0.f; a1[u] = 0.f;
    }
    for (int j = 0; j < 32; j++) {
      float4 r = rpe4[j];
      float wb = rpeB[j];
#pragma unroll
      for (int u = 0; u < 16; u++) {
        float hv = fmaf(r.x, ty[u], fmaf(r.y, tx[u], r.z));
        hv = fmaxf(hv, 0.f);
        a0[u] = fmaf(r.w, hv, a0[u]);
        a1[u] = fmaf(wb, hv, a1[u]);
      }
    }
    float* b0p = bias0 + i * 68 + n0;
    float* b1p = bias1 + i * 68 + n0;
#pragma unroll
    for (int u = 0; u < 16; u++) { b0p[u] = a0[u]; b1p[u] = a1[u]; }
  }
  // no barrier: each wave wrote and will read only its own 16 rows

  const int lr = lane & 15, kg = lane >> 4;
  const int mrow = m0 + w * 16 + lr;
  const float scale = 0.17677669529663687f;   // 1/sqrt(32)
  ushort* pb = Pbuf[w];

  f32x4 oacc[2][2];
#pragma unroll
  for (int gh = 0; gh < 2; gh++)
#pragma unroll
    for (int cf = 0; cf < 2; cf++) oacc[gh][cf] = (f32x4){0.f, 0.f, 0.f, 0.f};

#pragma unroll
  for (int gh = 0; gh < 2; gh++) {
    // S = Q K^T  (K=32 contraction -> one mfma per 16-col frag)
    bf16x8 a = *(const bf16x8*)(qpk +
        ((size_t)(b * 3136 + mrow) * 256 + g * 64 + gh * 32 + kg * 8));
    const ushort* kbase = kpk + (size_t)(b * 8 + g * 2 + gh) * 2048;
    f32x4 s[4];
#pragma unroll
    for (int nf = 0; nf < 4; nf++) {
      bf16x8 bfr = *(const bf16x8*)(kbase + (size_t)(kg * 64 + nf * 16 + lr) * 8);
      s[nf] = __builtin_amdgcn_mfma_f32_16x16x32_bf16(
          a, bfr, (f32x4){0.f, 0.f, 0.f, 0.f}, 0, 0, 0);
    }
    // scale + bias (C-layout: row = w*16 + kg*4 + j, col = nf*16 + lr)
    const float* bt = gh ? bias1 : bias0;
#pragma unroll
    for (int nf = 0; nf < 4; nf++)
#pragma unroll
      for (int j = 0; j < 4; j++)
        s[nf][j] = fmaf(s[nf][j], scale,
                        bt[(w * 16 + kg * 4 + j) * 68 + nf * 16 + lr]);
    // softmax over n (4 frags x 16 lanes)
#pragma unroll
    for (int j = 0; j < 4; j++) {
      float m1 = fmaxf(fmaxf(s[0][j], s[1][j]), fmaxf(s[2][j], s[3][j]));
#pragma unroll
      for (int o = 8; o >= 1; o >>= 1) m1 = fmaxf(m1, __shfl_xor(m1, o));
      float ss = 0.f;
#pragma unroll
      for (int nf = 0; nf < 4; nf++) {
        float e = __expf(s[nf][j] - m1);
        s[nf][j] = e;
        ss += e;
      }
#pragma unroll
      for (int o = 8; o >= 1; o >>= 1) ss += __shfl_xor(ss, o);
      float inv = 1.f / ss;
#pragma unroll
      for (int nf = 0; nf < 4; nf++) s[nf][j] *= inv;
    }
    // P -> wave-private LDS [16 rows][72]
#pragma unroll
    for (int nf = 0; nf < 4; nf++)
#pragma unroll
      for (int j = 0; j < 4; j++)
        pb[(kg * 4 + j) * 72 + nf * 16 + lr] = f2bf(s[nf][j]);
    // PV: out[i][c] += P[i][n] V[n][c]
    const ushort* vbase = vpk + (size_t)(b * 8 + g * 2 + gh) * 2048;
#pragma unroll
    for (int ks = 0; ks < 2; ks++) {
      bf16x8 pa = *(const bf16x8*)(pb + lr * 72 + ks * 32 + kg * 8);
#pragma unroll
      for (int cf = 0; cf < 2; cf++) {
        bf16x8 vb = *(const bf16x8*)(vbase +
            (size_t)((ks * 4 + kg) * 32 + cf * 16 + lr) * 8);
        oacc[gh][cf] = __builtin_amdgcn_mfma_f32_16x16x32_bf16(
            pa, vb, oacc[gh][cf], 0, 0, 0);
      }
    }
  }

  // out tile -> bias0 region (same 272B row stride -> wave-private rows)
  ushort* outb = (ushort*)bias0;
#pragma unroll
  for (int gh = 0; gh < 2; gh++)
#pragma unroll
    for (int cf = 0; cf < 2; cf++)
#pragma unroll
      for (int j = 0; j < 4; j++)
        outb[(w * 16 + kg * 4 + j) * 136 + gh * 32 + cf * 16 + lr] =
            f2bf(oacc[gh][cf][j]);
  __syncthreads();
  // coalesced store: 64 rows x 64 c (this group's 64 channels)
#pragma unroll
  for (int r2 = 0; r2 < 2; r2++) {
    int row = (t >> 3) + r2 * 32;
    int chunk = t & 7;
    bf16x8 v8 = *(const bf16x8*)(outb + row * 136 + chunk * 8);
    *(bf16x8*)(attnpk +
               ((size_t)(b * 3136 + m0 + row) * 256 + g * 64 + chunk * 8)) = v8;
  }
}

// ---------------------------------------------------------------------------
extern "C" void kernel_launch(void* const* d_in, const int* in_sizes, int n_in,
                              void* d_out, int out_size, void* d_ws,
                              size_t ws_size, hipStream_t stream) {
  const float* x       = (const float*)d_in[0];
  const float* patch_w = (const float*)d_in[1];
  const float* patch_b = (const float*)d_in[2];
  const float* ln1_g   = (const float*)d_in[3];
  const float* ln1_b   = (const float*)d_in[4];
  const float* wq      = (const float*)d_in[5];
  const float* bq      = (const float*)d_in[6];
  const float* wk      = (const float*)d_in[7];
  const float* bk      = (const float*)d_in[8];
  const float* wv      = (const float*)d_in[9];
  const float* bv      = (const float*)d_in[10];
  const float* wo      = (const float*)d_in[11];
  const float* bo      = (const float*)d_in[12];
  const float* off_dw_w = (const float*)d_in[13];
  const float* off_dw_b = (const float*)d_in[14];
  const float* off_ln_g = (const float*)d_in[15];
  const float* off_ln_b = (const float*)d_in[16];
  const float* off_pw_w = (const float*)d_in[17];
  const float* rpe_w1  = (const float*)d_in[18];
  const float* rpe_b1  = (const float*)d_in[19];
  const float* rpe_w2  = (const float*)d_in[20];

  float* ws = (float*)d_ws;
  ushort* featb = (ushort*)(ws + OFF_FEATB);   // bf16 [m][c]
  ushort* attnpk = featb;                      // reuse (feat dead after sample)
  ushort* qpk = (ushort*)(ws + OFF_QPK);       // bf16 [m][c]
  float* q    = ws + OFF_Q;                    // fp32 [c][m]
  float* posw = ws + OFF_POS;
  float* xs   = ws + OFF_XS;
  float* convo = ws + OFF_XS;                  // alias xs (dead before xs)
  ushort* kpk = (ushort*)(ws + OFF_KPK);
  ushort* vpk = (ushort*)(ws + OFF_VPK);
  ushort* pwp = (ushort*)(ws + OFF_PWP);
  ushort* wqp = (ushort*)(ws + OFF_WQP);
  ushort* wop = (ushort*)(ws + OFF_WOP);
  float* wkT  = ws + OFF_WKT;
  float* wvT  = ws + OFF_WVT;

  float* y = (float*)d_out;
  float* out_pos = y + 6422528;
  float* out_ref = out_pos + 4096;

  // P: weight packs / transposes
  hipLaunchKernelGGL(k_pack, dim3(256, 5), dim3(256), 0, stream,
                     patch_w, wq, wk, wv, wo, pwp, wqp, wop, wkT, wvT);
  // A: patch embed conv (MFMA) + LN -> feat bf16 [m][c]
  hipLaunchKernelGGL(k_patch_mfma, dim3(392), dim3(256), 0, stream,
                     x, pwp, patch_b, ln1_g, ln1_b, featb);
  // B: q = wq @ feat + bq  -> fp32 [c][m] + bf16 pack [m][c]
  hipLaunchKernelGGL(k_gemm_mfma, dim3(392), dim3(512), 0, stream,
                     featb, wqp, bq, q, qpk);
  // C1: offset depthwise conv
  hipLaunchKernelGGL(k_offset_conv, dim3(32, 32), dim3(128), 0, stream,
                     q, off_dw_w, convo);
  // C2: offset post (LN + GELU + pointwise + tanh) -> pos
  hipLaunchKernelGGL(k_offset_post, dim3(16, 32), dim3(256), 0, stream,
                     convo, off_dw_b, off_ln_g, off_ln_b, off_pw_w,
                     posw, out_pos, out_ref);
  // D: bilinear sampling (bf16 feat, coalesced)
  hipLaunchKernelGGL(k_sample, dim3(16, 32), dim3(256), 0, stream,
                     featb, posw, xs);
  // E: k, v projections -> bf16 B-frag packs
  hipLaunchKernelGGL(k_kv, dim3(64, 8), dim3(256), 0, stream,
                     xs, wkT, bk, wvT, bv, kpk, vpk);
  // F: MFMA attention -> bf16 pack [m][c]
  hipLaunchKernelGGL(k_attn_mfma, dim3(49, 32), dim3(256), 0, stream,
                     qpk, kpk, vpk, posw, rpe_w1, rpe_b1, rpe_w2, attnpk);
  // G: y = wo @ attn_out + bo  (fp32 [c][m] = d_out)
  hipLaunchKernelGGL(k_gemm_mfma, dim3(392), dim3(512), 0, stream,
                     attnpk, wop, bo, y, (ushort*)nullptr);
}